// Round 1
// baseline (607.651 us; speedup 1.0000x reference)
//
#include <hip/hip_runtime.h>
#include <hip/hip_bf16.h>
#include <cstdint>

typedef __bf16 bf16x8 __attribute__((ext_vector_type(8)));
typedef float f32x4 __attribute__((ext_vector_type(4)));
typedef unsigned short u16x8 __attribute__((ext_vector_type(8)));
typedef unsigned short u16x4 __attribute__((ext_vector_type(4)));

__device__ __forceinline__ unsigned short f2bf(float f) {
  unsigned int u = __float_as_uint(f);
  u += 0x7FFFu + ((u >> 16) & 1u);
  return (unsigned short)(u >> 16);
}
__device__ __forceinline__ float bf2f(unsigned short h) {
  return __uint_as_float(((unsigned int)h) << 16);
}
__device__ __forceinline__ float sigmoidf_(float x) { return 1.f / (1.f + __expf(-x)); }
__device__ __forceinline__ float siluf_(float x) { return x * sigmoidf_(x); }

#define GLOAD_LDS16(gsrc, ldst) \
  __builtin_amdgcn_global_load_lds((const __attribute__((address_space(1))) void*)(gsrc), \
                                   (__attribute__((address_space(3))) void*)(ldst), 16, 0, 0)

// ---------------------------------------------------------------------------
// Generic bf16 GEMM: C[M,N](bf16) = A(bf16,[M,K1]|[M,K2] two-segment) @ Bt^T
// Bt stored transposed: [N][Ktot] bf16. Tiles 128x128, BK=64, 4 waves.
// ---------------------------------------------------------------------------
__global__ __launch_bounds__(256) void gemm_bf16(
    const unsigned short* __restrict__ A1, int lda1, long long a1_bs, int K1,
    const unsigned short* __restrict__ A2, int lda2, int K2,
    const unsigned short* __restrict__ Bt, int ldb, long long bt_bs,
    unsigned short* __restrict__ C, int ldc, long long c_bs)
{
  const int g = blockIdx.z;
  A1 += (long long)g * a1_bs;
  Bt += (long long)g * bt_bs;
  C  += (long long)g * c_bs;
  const int tm = blockIdx.y * 128;
  const int tn = blockIdx.x * 128;
  __shared__ unsigned short As[128 * 64];
  __shared__ unsigned short Bs[128 * 64];
  const int tid = threadIdx.x;
  const int lane = tid & 63;
  const int wave = tid >> 6;
  const int wm = (wave >> 1) * 64, wn = (wave & 1) * 64;
  const int lrow = lane & 15, lk = (lane >> 4) * 8;

  f32x4 acc[4][4] = {};

  const int Ktot = K1 + K2;
  for (int kt = 0; kt < Ktot; kt += 64) {
    const unsigned short* Ab; int alda, kloc;
    if (kt < K1) { Ab = A1; alda = lda1; kloc = kt; }
    else         { Ab = A2; alda = lda2; kloc = kt - K1; }
#pragma unroll
    for (int j = 0; j < 4; ++j) {
      const int cb = j * 256 + wave * 64;      // chunk base: uniform per wave
      const int chunk = cb + lane;
      const int row = chunk >> 3, kc = chunk & 7;
      GLOAD_LDS16(Ab + (long long)(tm + row) * alda + kloc + kc * 8, &As[cb * 8]);
    }
#pragma unroll
    for (int j = 0; j < 4; ++j) {
      const int cb = j * 256 + wave * 64;
      const int chunk = cb + lane;
      const int row = chunk >> 3, kc = chunk & 7;
      GLOAD_LDS16(Bt + (long long)(tn + row) * ldb + kt + kc * 8, &Bs[cb * 8]);
    }
    __syncthreads();
#pragma unroll
    for (int kk = 0; kk < 64; kk += 32) {
      bf16x8 a[4], b[4];
#pragma unroll
      for (int m = 0; m < 4; ++m)
        a[m] = *(const bf16x8*)&As[(wm + m * 16 + lrow) * 64 + kk + lk];
#pragma unroll
      for (int n = 0; n < 4; ++n)
        b[n] = *(const bf16x8*)&Bs[(wn + n * 16 + lrow) * 64 + kk + lk];
#pragma unroll
      for (int m = 0; m < 4; ++m)
#pragma unroll
        for (int n = 0; n < 4; ++n)
          acc[m][n] = __builtin_amdgcn_mfma_f32_16x16x32_bf16(a[m], b[n], acc[m][n], 0, 0, 0);
    }
    __syncthreads();
  }

#pragma unroll
  for (int m = 0; m < 4; ++m) {
    const int r0 = tm + wm + m * 16 + (lane >> 4) * 4;
#pragma unroll
    for (int n = 0; n < 4; ++n) {
      const int col = tn + wn + n * 16 + (lane & 15);
#pragma unroll
      for (int i = 0; i < 4; ++i)
        C[(long long)(r0 + i) * ldc + col] = f2bf(acc[m][n][i]);
    }
  }
}

// ---------------------------------------------------------------------------
// fp32 -> bf16 elementwise cast (4 elems / thread)
// ---------------------------------------------------------------------------
__global__ void cvt_bf16_k(const float* __restrict__ src, unsigned short* __restrict__ dst, int n4) {
  int i = blockIdx.x * 256 + threadIdx.x;
  if (i >= n4) return;
  float4 v = ((const float4*)src)[i];
  u16x4 o;
  o.x = f2bf(v.x); o.y = f2bf(v.y); o.z = f2bf(v.z); o.w = f2bf(v.w);
  ((u16x4*)dst)[i] = o;
}

// ---------------------------------------------------------------------------
// Batched transpose + cast: src fp32 [z][R][C] -> dst bf16 [z][C][R]
// ---------------------------------------------------------------------------
__global__ void transpose_cvt(const float* __restrict__ src, unsigned short* __restrict__ dst,
                              int R, int C) {
  __shared__ float t[32][33];
  const long long bOff = (long long)blockIdx.z * R * C;
  src += bOff; dst += bOff;
  const int c0 = blockIdx.x * 32, r0 = blockIdx.y * 32;
  const int tx = threadIdx.x, ty = threadIdx.y;  // (32,8)
#pragma unroll
  for (int i = 0; i < 4; ++i) {
    int r = r0 + ty + i * 8, c = c0 + tx;
    if (r < R && c < C) t[ty + i * 8][tx] = src[(long long)r * C + c];
  }
  __syncthreads();
#pragma unroll
  for (int i = 0; i < 4; ++i) {
    int c = c0 + ty + i * 8, r = r0 + tx;
    if (r < R && c < C) dst[(long long)c * R + r] = f2bf(t[tx][ty + i * 8]);
  }
}

// ---------------------------------------------------------------------------
// Branches 2 (action, K=32, normalized) and 3 (d_emb, K=16): tiny-K GEMM
// fused with RMSNorm(512)+SiLU, writes x cols [1024..2047] bf16.
// ---------------------------------------------------------------------------
__global__ __launch_bounds__(256) void branch23_k(
    const float* __restrict__ action, const float* __restrict__ demb,
    const float* __restrict__ W2, const float* __restrict__ b2, const float* __restrict__ g2,
    const float* __restrict__ W3, const float* __restrict__ b3, const float* __restrict__ g3,
    unsigned short* __restrict__ x)
{
  const int row = blockIdx.x, br = blockIdx.y;
  const int K = br ? 16 : 32;
  const float* W  = br ? W3 : W2;
  const float* bb = br ? b3 : b2;
  const float* gg = br ? g3 : g2;
  __shared__ float a[32];
  __shared__ float red[4];
  const int tid = threadIdx.x, lane = tid & 63, wave = tid >> 6;
  if (tid < K) {
    float t = br ? demb[(long long)row * 16 + tid] : action[(long long)row * 32 + tid];
    if (!br) t = t / fmaxf(fabsf(t), 1.f);
    a[tid] = t;
  }
  __syncthreads();
  float y0 = bb[tid], y1 = bb[tid + 256];
  for (int k = 0; k < K; ++k) {
    float av = a[k];
    y0 += av * W[k * 512 + tid];
    y1 += av * W[k * 512 + tid + 256];
  }
  float ss = y0 * y0 + y1 * y1;
  for (int o = 32; o > 0; o >>= 1) ss += __shfl_xor(ss, o);
  if (lane == 0) red[wave] = ss;
  __syncthreads();
  float ms = (red[0] + red[1] + red[2] + red[3]) * (1.f / 512.f);
  float sc = rsqrtf(ms + 1e-4f);
  unsigned short* xr = x + (long long)row * 2048 + 1024 + br * 512;
  xr[tid]       = f2bf(siluf_(y0 * sc * gg[tid]));
  xr[tid + 256] = f2bf(siluf_(y1 * sc * gg[tid + 256]));
}

// ---------------------------------------------------------------------------
// Branch 0/1 epilogue: y(bf16) + b -> RMSNorm(512) -> SiLU -> x cols [0..1023]
// ---------------------------------------------------------------------------
__global__ __launch_bounds__(256) void epi_branch_k(
    const unsigned short* __restrict__ y,
    const float* __restrict__ b0, const float* __restrict__ g0,
    const float* __restrict__ b1, const float* __restrict__ g1,
    unsigned short* __restrict__ x)
{
  const int row = blockIdx.x, br = blockIdx.y;
  const float* bb = br ? b1 : b0;
  const float* gg = br ? g1 : g0;
  const unsigned short* yr = y + (long long)row * 4096 + br * 512;
  __shared__ float red[4];
  const int tid = threadIdx.x, lane = tid & 63, wave = tid >> 6;
  float v0 = bf2f(yr[tid]) + bb[tid];
  float v1 = bf2f(yr[tid + 256]) + bb[tid + 256];
  float ss = v0 * v0 + v1 * v1;
  for (int o = 32; o > 0; o >>= 1) ss += __shfl_xor(ss, o);
  if (lane == 0) red[wave] = ss;
  __syncthreads();
  float ms = (red[0] + red[1] + red[2] + red[3]) * (1.f / 512.f);
  float sc = rsqrtf(ms + 1e-4f);
  unsigned short* xr = x + (long long)row * 2048 + br * 512;
  xr[tid]       = f2bf(siluf_(v0 * sc * gg[tid]));
  xr[tid + 256] = f2bf(siluf_(v1 * sc * gg[tid + 256]));
}

// ---------------------------------------------------------------------------
// Full-width (4096) epilogue: y(bf16) + bias -> RMSNorm -> SiLU -> h(bf16)
// ---------------------------------------------------------------------------
__global__ __launch_bounds__(256) void epi_full_k(
    const unsigned short* __restrict__ y, const float* __restrict__ bias,
    const float* __restrict__ gw, unsigned short* __restrict__ h)
{
  const int row = blockIdx.x;
  __shared__ float v[4096];
  __shared__ float red[4];
  const int tid = threadIdx.x, lane = tid & 63, wave = tid >> 6;
  const u16x8* yv = (const u16x8*)(y + (long long)row * 4096);
  float ss = 0.f;
#pragma unroll
  for (int j = 0; j < 2; ++j) {
    int vi = j * 256 + tid;
    u16x8 t = yv[vi];
#pragma unroll
    for (int e = 0; e < 8; ++e) {
      float f = bf2f(t[e]) + bias[vi * 8 + e];
      v[vi * 8 + e] = f;
      ss += f * f;
    }
  }
  for (int o = 32; o > 0; o >>= 1) ss += __shfl_xor(ss, o);
  if (lane == 0) red[wave] = ss;
  __syncthreads();
  float ms = (red[0] + red[1] + red[2] + red[3]) * (1.f / 4096.f);
  float sc = rsqrtf(ms + 1e-4f);
  u16x8* hv = (u16x8*)(h + (long long)row * 4096);
#pragma unroll
  for (int j = 0; j < 2; ++j) {
    int vi = j * 256 + tid;
    u16x8 o8;
#pragma unroll
    for (int e = 0; e < 8; ++e) {
      float t = v[vi * 8 + e] * sc * gw[vi * 8 + e];
      o8[e] = f2bf(siluf_(t));
    }
    hv[vi] = o8;
  }
}

// ---------------------------------------------------------------------------
// Final: gates(bf16) + bg -> GRU combine with original deter -> out fp32
// ---------------------------------------------------------------------------
__global__ __launch_bounds__(256) void final_k(
    const unsigned short* __restrict__ gates, const float* __restrict__ bg,
    const float* __restrict__ deter, float* __restrict__ out)
{
  const long long idx = ((long long)blockIdx.x * 256 + threadIdx.x) * 8;
  const int c = (int)(idx & 4095);
  const int r = (int)(idx >> 12);
  const int g = c >> 9, o = c & 511;
  const long long gbase = (long long)r * 12288 + g * 1536 + o;
  u16x8 rs = *(const u16x8*)&gates[gbase];
  u16x8 cd = *(const u16x8*)&gates[gbase + 512];
  u16x8 up = *(const u16x8*)&gates[gbase + 1024];
  const float* bgp = bg + g * 1536 + o;
  float4 d0 = *(const float4*)&deter[idx];
  float4 d1 = *(const float4*)&deter[idx + 4];
  float dv[8] = {d0.x, d0.y, d0.z, d0.w, d1.x, d1.y, d1.z, d1.w};
  float ov[8];
#pragma unroll
  for (int j = 0; j < 8; ++j) {
    float reset = sigmoidf_(bf2f(rs[j]) + bgp[j]);
    float cand  = tanhf(reset * (bf2f(cd[j]) + bgp[512 + j]));
    float upd   = sigmoidf_(bf2f(up[j]) + bgp[1024 + j] - 1.f);
    ov[j] = upd * cand + (1.f - upd) * dv[j];
  }
  *(float4*)&out[idx]     = make_float4(ov[0], ov[1], ov[2], ov[3]);
  *(float4*)&out[idx + 4] = make_float4(ov[4], ov[5], ov[6], ov[7]);
}

// ---------------------------------------------------------------------------
extern "C" void kernel_launch(void* const* d_in, const int* in_sizes, int n_in,
                              void* d_out, int out_size, void* d_ws, size_t ws_size,
                              hipStream_t stream) {
  const float* stoch  = (const float*)d_in[0];
  const float* deter  = (const float*)d_in[1];
  const float* action = (const float*)d_in[2];
  const float* demb   = (const float*)d_in[3];
  const float* W0 = (const float*)d_in[4];
  const float* b0 = (const float*)d_in[5];
  const float* g0 = (const float*)d_in[6];
  const float* W1 = (const float*)d_in[7];
  const float* b1 = (const float*)d_in[8];
  const float* g1 = (const float*)d_in[9];
  const float* W2 = (const float*)d_in[10];
  const float* b2 = (const float*)d_in[11];
  const float* g2 = (const float*)d_in[12];
  const float* W3 = (const float*)d_in[13];
  const float* b3 = (const float*)d_in[14];
  const float* g3 = (const float*)d_in[15];
  const float* Wh0 = (const float*)d_in[16];
  const float* bh0 = (const float*)d_in[17];
  const float* gh0 = (const float*)d_in[18];
  const float* Wh1 = (const float*)d_in[19];
  const float* bh1 = (const float*)d_in[20];
  const float* gh1 = (const float*)d_in[21];
  const float* Wg  = (const float*)d_in[22];
  const float* bg  = (const float*)d_in[23];
  float* out = (float*)d_out;

  // workspace layout (bytes). gates (100.7MB) overlaps region A, whose
  // occupants (W0t,W1t,deterB,stochB,x,y) are all dead before the gates GEMM.
  char* ws = (char*)d_ws;
  unsigned short* gatesB = (unsigned short*)(ws + 0);
  unsigned short* W0t    = (unsigned short*)(ws + 0);
  unsigned short* W1t    = (unsigned short*)(ws + 4194304);
  unsigned short* deterB = (unsigned short*)(ws + 5242880);
  unsigned short* stochB = (unsigned short*)(ws + 38797312);
  unsigned short* xB     = (unsigned short*)(ws + 47185920);
  unsigned short* yB     = (unsigned short*)(ws + 63963136);
  unsigned short* Wh0t   = (unsigned short*)(ws + 100663296);
  unsigned short* Wh1t   = (unsigned short*)(ws + 121634816);
  unsigned short* Wgt    = (unsigned short*)(ws + 125829120);
  unsigned short* hB     = (unsigned short*)(ws + 138412032);
  (void)in_sizes; (void)n_in; (void)out_size; (void)ws_size;

  dim3 b256(256);
  dim3 tb(32, 8);
  // conversions + weight transposes (per launch; deterministic)
  cvt_bf16_k<<<dim3(16384), b256, 0, stream>>>(deter, deterB, 4194304);
  cvt_bf16_k<<<dim3(4096),  b256, 0, stream>>>(stoch, stochB, 1048576);
  transpose_cvt<<<dim3(16, 128, 1), tb, 0, stream>>>(W0,  W0t,  4096, 512);
  transpose_cvt<<<dim3(16, 32, 1),  tb, 0, stream>>>(W1,  W1t,  1024, 512);
  transpose_cvt<<<dim3(16, 80, 8),  tb, 0, stream>>>(Wh0, Wh0t, 2560, 512);
  transpose_cvt<<<dim3(16, 16, 8),  tb, 0, stream>>>(Wh1, Wh1t, 512,  512);
  transpose_cvt<<<dim3(48, 16, 8),  tb, 0, stream>>>(Wg,  Wgt,  512,  1536);
  // phase A: input branches
  gemm_bf16<<<dim3(4, 32, 1), b256, 0, stream>>>(deterB, 4096, 0, 4096, nullptr, 0, 0,
                                                 W0t, 4096, 0, yB, 4096, 0);
  gemm_bf16<<<dim3(4, 32, 1), b256, 0, stream>>>(stochB, 1024, 0, 1024, nullptr, 0, 0,
                                                 W1t, 1024, 0, yB + 512, 4096, 0);
  branch23_k<<<dim3(4096, 2), b256, 0, stream>>>(action, demb, W2, b2, g2, W3, b3, g3, xB);
  epi_branch_k<<<dim3(4096, 2), b256, 0, stream>>>(yB, b0, g0, b1, g1, xB);
  // hidden block layer 0: [deter_blk | x] @ Wh0
  gemm_bf16<<<dim3(4, 32, 8), b256, 0, stream>>>(deterB, 4096, 512, 512, xB, 2048, 2048,
                                                 Wh0t, 2560, 512LL * 2560, yB, 4096, 512);
  epi_full_k<<<dim3(4096), b256, 0, stream>>>(yB, bh0, gh0, hB);
  // hidden block layer 1
  gemm_bf16<<<dim3(4, 32, 8), b256, 0, stream>>>(hB, 4096, 512, 512, nullptr, 0, 0,
                                                 Wh1t, 512, 512LL * 512, yB, 4096, 512);
  epi_full_k<<<dim3(4096), b256, 0, stream>>>(yB, bh1, gh1, hB);
  // GRU gates block GEMM -> gates buffer (bf16)
  gemm_bf16<<<dim3(12, 32, 8), b256, 0, stream>>>(hB, 4096, 512, 512, nullptr, 0, 0,
                                                  Wgt, 512, 1536LL * 512, gatesB, 12288, 1536);
  final_k<<<dim3(8192), b256, 0, stream>>>(gatesB, bg, deter, out);
}

// Round 2
// 594.092 us; speedup vs baseline: 1.0228x; 1.0228x over previous
//
#include <hip/hip_runtime.h>
#include <hip/hip_bf16.h>
#include <cstdint>

typedef __bf16 bf16x8 __attribute__((ext_vector_type(8)));
typedef float f32x4 __attribute__((ext_vector_type(4)));
typedef unsigned short u16x8 __attribute__((ext_vector_type(8)));
typedef unsigned short u16x4 __attribute__((ext_vector_type(4)));

__device__ __forceinline__ unsigned short f2bf(float f) {
  unsigned int u = __float_as_uint(f);
  u += 0x7FFFu + ((u >> 16) & 1u);
  return (unsigned short)(u >> 16);
}
__device__ __forceinline__ float bf2f(unsigned short h) {
  return __uint_as_float(((unsigned int)h) << 16);
}
__device__ __forceinline__ float sigmoidf_(float x) { return 1.f / (1.f + __expf(-x)); }
__device__ __forceinline__ float siluf_(float x) { return x * sigmoidf_(x); }

#define GLOAD_LDS16(gsrc, ldst) \
  __builtin_amdgcn_global_load_lds((const __attribute__((address_space(1))) void*)(gsrc), \
                                   (__attribute__((address_space(3))) void*)(ldst), 16, 0, 0)

// ---------------------------------------------------------------------------
// Core bf16 GEMM tile: C[128,128](bf16) = A(two-segment [.,K1]|[.,K2]) @ Bt^T
// Double-buffered LDS, prefetch-before-compute (T3 minimum 2-phase recipe):
// STAGE(buf^1, t+1) issued BEFORE ds_read+MFMA of buf; single __syncthreads
// (emits vmcnt(0)+lgkmcnt(0) drain) per K-step -> next-tile HBM latency hides
// under current tile's compute.
// ---------------------------------------------------------------------------
__device__ __forceinline__ void gemm_core(
    const unsigned short* __restrict__ A1, int lda1, int K1,
    const unsigned short* __restrict__ A2, int lda2, int K2,
    const unsigned short* __restrict__ Bt, int ldb,
    unsigned short* __restrict__ C, int ldc,
    int tm, int tn, unsigned short* As, unsigned short* Bs)
{
  const int tid = threadIdx.x;
  const int lane = tid & 63;
  const int wave = tid >> 6;
  const int wm = (wave >> 1) * 64, wn = (wave & 1) * 64;
  const int lrow = lane & 15, lk = (lane >> 4) * 8;
  const int Ktot = K1 + K2;
  const int nt = Ktot >> 6;

  f32x4 acc[4][4] = {};

  auto stage = [&](int buf, int kt) {
    const unsigned short* Ab; int alda, kloc;
    if (kt >= K1) { Ab = A2; alda = lda2; kloc = kt - K1; }
    else          { Ab = A1; alda = lda1; kloc = kt; }
    unsigned short* Ad = As + buf * 8192;
    unsigned short* Bd = Bs + buf * 8192;
#pragma unroll
    for (int j = 0; j < 4; ++j) {
      const int cb = j * 256 + wave * 64;         // wave-uniform chunk base
      const int chunk = cb + lane;
      const int row = chunk >> 3, kc = chunk & 7;
      GLOAD_LDS16(Ab + (long long)(tm + row) * alda + kloc + kc * 8, Ad + cb * 8);
    }
#pragma unroll
    for (int j = 0; j < 4; ++j) {
      const int cb = j * 256 + wave * 64;
      const int chunk = cb + lane;
      const int row = chunk >> 3, kc = chunk & 7;
      GLOAD_LDS16(Bt + (long long)(tn + row) * ldb + kt + kc * 8, Bd + cb * 8);
    }
  };

  stage(0, 0);
  __syncthreads();                         // drains vmcnt(0), publishes buf 0
  int cur = 0;
  for (int t = 0; t < nt; ++t) {
    if (t + 1 < nt) stage(cur ^ 1, (t + 1) << 6);   // prefetch next tile
    const unsigned short* Ar = As + cur * 8192;
    const unsigned short* Br = Bs + cur * 8192;
#pragma unroll
    for (int kk = 0; kk < 64; kk += 32) {
      bf16x8 a[4], b[4];
#pragma unroll
      for (int m = 0; m < 4; ++m)
        a[m] = *(const bf16x8*)&Ar[(wm + m * 16 + lrow) * 64 + kk + lk];
#pragma unroll
      for (int n = 0; n < 4; ++n)
        b[n] = *(const bf16x8*)&Br[(wn + n * 16 + lrow) * 64 + kk + lk];
#pragma unroll
      for (int m = 0; m < 4; ++m)
#pragma unroll
        for (int n = 0; n < 4; ++n)
          acc[m][n] = __builtin_amdgcn_mfma_f32_16x16x32_bf16(a[m], b[n], acc[m][n], 0, 0, 0);
    }
    __syncthreads();                       // vmcnt(0)+lgkmcnt(0)+barrier
    cur ^= 1;
  }

#pragma unroll
  for (int m = 0; m < 4; ++m) {
    const int r0 = tm + wm + m * 16 + (lane >> 4) * 4;
#pragma unroll
    for (int n = 0; n < 4; ++n) {
      const int col = tn + wn + n * 16 + (lane & 15);
#pragma unroll
      for (int i = 0; i < 4; ++i)
        C[(long long)(r0 + i) * ldc + col] = f2bf(acc[m][n][i]);
    }
  }
}

// Generic batched (z) two-segment GEMM
__global__ __launch_bounds__(256) void gemm_bf16(
    const unsigned short* __restrict__ A1, int lda1, long long a1_bs, int K1,
    const unsigned short* __restrict__ A2, int lda2, int K2,
    const unsigned short* __restrict__ Bt, int ldb, long long bt_bs,
    unsigned short* __restrict__ C, int ldc, long long c_bs)
{
  __shared__ unsigned short As[2 * 8192];
  __shared__ unsigned short Bs[2 * 8192];
  const int g = blockIdx.z;
  gemm_core(A1 + (long long)g * a1_bs, lda1, K1, A2, lda2, K2,
            Bt + (long long)g * bt_bs, ldb,
            C + (long long)g * c_bs, ldc,
            blockIdx.y * 128, blockIdx.x * 128, As, Bs);
}

// Two independent GEMM configs packed into one launch (z selects)
struct GCfg {
  const unsigned short* A; int lda; int K;
  const unsigned short* Bt; int ldb;
  unsigned short* C; int ldc;
};
__global__ __launch_bounds__(256) void gemm_branch2(GCfg c0, GCfg c1) {
  __shared__ unsigned short As[2 * 8192];
  __shared__ unsigned short Bs[2 * 8192];
  GCfg c = blockIdx.z ? c1 : c0;
  gemm_core(c.A, c.lda, c.K, nullptr, 0, 0, c.Bt, c.ldb, c.C, c.ldc,
            blockIdx.y * 128, blockIdx.x * 128, As, Bs);
}

// ---------------------------------------------------------------------------
// fp32 -> bf16 cast for two buffers in one launch (4 elems / thread)
// ---------------------------------------------------------------------------
__global__ void cvt2_bf16_k(const float* __restrict__ sa, unsigned short* __restrict__ da, int n4a,
                            const float* __restrict__ sb, unsigned short* __restrict__ db, int n4b) {
  int i = blockIdx.x * 256 + threadIdx.x;
  const float* s; unsigned short* d;
  if (i < n4a) { s = sa; d = da; }
  else { i -= n4a; if (i >= n4b) return; s = sb; d = db; }
  float4 v = ((const float4*)s)[i];
  u16x4 o;
  o.x = f2bf(v.x); o.y = f2bf(v.y); o.z = f2bf(v.z); o.w = f2bf(v.w);
  ((u16x4*)d)[i] = o;
}

// ---------------------------------------------------------------------------
// Batched transpose + cast: src fp32 [z][R][C] -> dst bf16 [z][C][R]
// ---------------------------------------------------------------------------
__global__ void transpose_cvt(const float* __restrict__ src, unsigned short* __restrict__ dst,
                              int R, int C) {
  __shared__ float t[32][33];
  const long long bOff = (long long)blockIdx.z * R * C;
  src += bOff; dst += bOff;
  const int c0 = blockIdx.x * 32, r0 = blockIdx.y * 32;
  const int tx = threadIdx.x, ty = threadIdx.y;  // (32,8)
#pragma unroll
  for (int i = 0; i < 4; ++i) {
    int r = r0 + ty + i * 8, c = c0 + tx;
    if (r < R && c < C) t[ty + i * 8][tx] = src[(long long)r * C + c];
  }
  __syncthreads();
#pragma unroll
  for (int i = 0; i < 4; ++i) {
    int c = c0 + ty + i * 8, r = r0 + tx;
    if (r < R && c < C) dst[(long long)c * R + r] = f2bf(t[tx][ty + i * 8]);
  }
}

// ---------------------------------------------------------------------------
// Branches 2 (action, K=32, normalized) and 3 (d_emb, K=16): tiny-K GEMM
// fused with RMSNorm(512)+SiLU, writes x cols [1024..2047] bf16.
// ---------------------------------------------------------------------------
__global__ __launch_bounds__(256) void branch23_k(
    const float* __restrict__ action, const float* __restrict__ demb,
    const float* __restrict__ W2, const float* __restrict__ b2, const float* __restrict__ g2,
    const float* __restrict__ W3, const float* __restrict__ b3, const float* __restrict__ g3,
    unsigned short* __restrict__ x)
{
  const int row = blockIdx.x, br = blockIdx.y;
  const int K = br ? 16 : 32;
  const float* W  = br ? W3 : W2;
  const float* bb = br ? b3 : b2;
  const float* gg = br ? g3 : g2;
  __shared__ float a[32];
  __shared__ float red[4];
  const int tid = threadIdx.x, lane = tid & 63, wave = tid >> 6;
  if (tid < K) {
    float t = br ? demb[(long long)row * 16 + tid] : action[(long long)row * 32 + tid];
    if (!br) t = t / fmaxf(fabsf(t), 1.f);
    a[tid] = t;
  }
  __syncthreads();
  float y0 = bb[tid], y1 = bb[tid + 256];
  for (int k = 0; k < K; ++k) {
    float av = a[k];
    y0 += av * W[k * 512 + tid];
    y1 += av * W[k * 512 + tid + 256];
  }
  float ss = y0 * y0 + y1 * y1;
  for (int o = 32; o > 0; o >>= 1) ss += __shfl_xor(ss, o);
  if (lane == 0) red[wave] = ss;
  __syncthreads();
  float ms = (red[0] + red[1] + red[2] + red[3]) * (1.f / 512.f);
  float sc = rsqrtf(ms + 1e-4f);
  unsigned short* xr = x + (long long)row * 2048 + 1024 + br * 512;
  xr[tid]       = f2bf(siluf_(y0 * sc * gg[tid]));
  xr[tid + 256] = f2bf(siluf_(y1 * sc * gg[tid + 256]));
}

// ---------------------------------------------------------------------------
// Branch 0/1 epilogue: y(bf16) + b -> RMSNorm(512) -> SiLU -> x cols [0..1023]
// ---------------------------------------------------------------------------
__global__ __launch_bounds__(256) void epi_branch_k(
    const unsigned short* __restrict__ y,
    const float* __restrict__ b0, const float* __restrict__ g0,
    const float* __restrict__ b1, const float* __restrict__ g1,
    unsigned short* __restrict__ x)
{
  const int row = blockIdx.x, br = blockIdx.y;
  const float* bb = br ? b1 : b0;
  const float* gg = br ? g1 : g0;
  const unsigned short* yr = y + (long long)row * 4096 + br * 512;
  __shared__ float red[4];
  const int tid = threadIdx.x, lane = tid & 63, wave = tid >> 6;
  float v0 = bf2f(yr[tid]) + bb[tid];
  float v1 = bf2f(yr[tid + 256]) + bb[tid + 256];
  float ss = v0 * v0 + v1 * v1;
  for (int o = 32; o > 0; o >>= 1) ss += __shfl_xor(ss, o);
  if (lane == 0) red[wave] = ss;
  __syncthreads();
  float ms = (red[0] + red[1] + red[2] + red[3]) * (1.f / 512.f);
  float sc = rsqrtf(ms + 1e-4f);
  unsigned short* xr = x + (long long)row * 2048 + br * 512;
  xr[tid]       = f2bf(siluf_(v0 * sc * gg[tid]));
  xr[tid + 256] = f2bf(siluf_(v1 * sc * gg[tid + 256]));
}

// ---------------------------------------------------------------------------
// Full-width (4096) epilogue: y(bf16) + bias -> RMSNorm -> SiLU -> h(bf16)
// ---------------------------------------------------------------------------
__global__ __launch_bounds__(256) void epi_full_k(
    const unsigned short* __restrict__ y, const float* __restrict__ bias,
    const float* __restrict__ gw, unsigned short* __restrict__ h)
{
  const int row = blockIdx.x;
  __shared__ float v[4096];
  __shared__ float red[4];
  const int tid = threadIdx.x, lane = tid & 63, wave = tid >> 6;
  const u16x8* yv = (const u16x8*)(y + (long long)row * 4096);
  float ss = 0.f;
#pragma unroll
  for (int j = 0; j < 2; ++j) {
    int vi = j * 256 + tid;
    u16x8 t = yv[vi];
#pragma unroll
    for (int e = 0; e < 8; ++e) {
      float f = bf2f(t[e]) + bias[vi * 8 + e];
      v[vi * 8 + e] = f;
      ss += f * f;
    }
  }
  for (int o = 32; o > 0; o >>= 1) ss += __shfl_xor(ss, o);
  if (lane == 0) red[wave] = ss;
  __syncthreads();
  float ms = (red[0] + red[1] + red[2] + red[3]) * (1.f / 4096.f);
  float sc = rsqrtf(ms + 1e-4f);
  u16x8* hv = (u16x8*)(h + (long long)row * 4096);
#pragma unroll
  for (int j = 0; j < 2; ++j) {
    int vi = j * 256 + tid;
    u16x8 o8;
#pragma unroll
    for (int e = 0; e < 8; ++e) {
      float t = v[vi * 8 + e] * sc * gw[vi * 8 + e];
      o8[e] = f2bf(siluf_(t));
    }
    hv[vi] = o8;
  }
}

// ---------------------------------------------------------------------------
// Final: gates(bf16) + bg -> GRU combine with original deter -> out fp32
// ---------------------------------------------------------------------------
__global__ __launch_bounds__(256) void final_k(
    const unsigned short* __restrict__ gates, const float* __restrict__ bg,
    const float* __restrict__ deter, float* __restrict__ out)
{
  const long long idx = ((long long)blockIdx.x * 256 + threadIdx.x) * 8;
  const int c = (int)(idx & 4095);
  const int r = (int)(idx >> 12);
  const int g = c >> 9, o = c & 511;
  const long long gbase = (long long)r * 12288 + g * 1536 + o;
  u16x8 rs = *(const u16x8*)&gates[gbase];
  u16x8 cd = *(const u16x8*)&gates[gbase + 512];
  u16x8 up = *(const u16x8*)&gates[gbase + 1024];
  const float* bgp = bg + g * 1536 + o;
  float4 d0 = *(const float4*)&deter[idx];
  float4 d1 = *(const float4*)&deter[idx + 4];
  float dv[8] = {d0.x, d0.y, d0.z, d0.w, d1.x, d1.y, d1.z, d1.w};
  float ov[8];
#pragma unroll
  for (int j = 0; j < 8; ++j) {
    float reset = sigmoidf_(bf2f(rs[j]) + bgp[j]);
    float cand  = tanhf(reset * (bf2f(cd[j]) + bgp[512 + j]));
    float upd   = sigmoidf_(bf2f(up[j]) + bgp[1024 + j] - 1.f);
    ov[j] = upd * cand + (1.f - upd) * dv[j];
  }
  *(float4*)&out[idx]     = make_float4(ov[0], ov[1], ov[2], ov[3]);
  *(float4*)&out[idx + 4] = make_float4(ov[4], ov[5], ov[6], ov[7]);
}

// ---------------------------------------------------------------------------
extern "C" void kernel_launch(void* const* d_in, const int* in_sizes, int n_in,
                              void* d_out, int out_size, void* d_ws, size_t ws_size,
                              hipStream_t stream) {
  const float* stoch  = (const float*)d_in[0];
  const float* deter  = (const float*)d_in[1];
  const float* action = (const float*)d_in[2];
  const float* demb   = (const float*)d_in[3];
  const float* W0 = (const float*)d_in[4];
  const float* b0 = (const float*)d_in[5];
  const float* g0 = (const float*)d_in[6];
  const float* W1 = (const float*)d_in[7];
  const float* b1 = (const float*)d_in[8];
  const float* g1 = (const float*)d_in[9];
  const float* W2 = (const float*)d_in[10];
  const float* b2 = (const float*)d_in[11];
  const float* g2 = (const float*)d_in[12];
  const float* W3 = (const float*)d_in[13];
  const float* b3 = (const float*)d_in[14];
  const float* g3 = (const float*)d_in[15];
  const float* Wh0 = (const float*)d_in[16];
  const float* bh0 = (const float*)d_in[17];
  const float* gh0 = (const float*)d_in[18];
  const float* Wh1 = (const float*)d_in[19];
  const float* bh1 = (const float*)d_in[20];
  const float* gh1 = (const float*)d_in[21];
  const float* Wg  = (const float*)d_in[22];
  const float* bg  = (const float*)d_in[23];
  float* out = (float*)d_out;

  // workspace layout (bytes). gates (100.7MB) overlaps region A, whose
  // occupants (W0t,W1t,deterB,stochB,x,y) are all dead before the gates GEMM.
  char* ws = (char*)d_ws;
  unsigned short* gatesB = (unsigned short*)(ws + 0);
  unsigned short* W0t    = (unsigned short*)(ws + 0);
  unsigned short* W1t    = (unsigned short*)(ws + 4194304);
  unsigned short* deterB = (unsigned short*)(ws + 5242880);
  unsigned short* stochB = (unsigned short*)(ws + 38797312);
  unsigned short* xB     = (unsigned short*)(ws + 47185920);
  unsigned short* yB     = (unsigned short*)(ws + 63963136);
  unsigned short* Wh0t   = (unsigned short*)(ws + 100663296);
  unsigned short* Wh1t   = (unsigned short*)(ws + 121634816);
  unsigned short* Wgt    = (unsigned short*)(ws + 125829120);
  unsigned short* hB     = (unsigned short*)(ws + 138412032);
  (void)in_sizes; (void)n_in; (void)out_size; (void)ws_size;

  dim3 b256(256);
  dim3 tb(32, 8);
  // conversions + weight transposes
  cvt2_bf16_k<<<dim3(20480), b256, 0, stream>>>(deter, deterB, 4194304,
                                                stoch, stochB, 1048576);
  transpose_cvt<<<dim3(16, 128, 1), tb, 0, stream>>>(W0,  W0t,  4096, 512);
  transpose_cvt<<<dim3(16, 32, 1),  tb, 0, stream>>>(W1,  W1t,  1024, 512);
  transpose_cvt<<<dim3(16, 80, 8),  tb, 0, stream>>>(Wh0, Wh0t, 2560, 512);
  transpose_cvt<<<dim3(16, 16, 8),  tb, 0, stream>>>(Wh1, Wh1t, 512,  512);
  transpose_cvt<<<dim3(48, 16, 8),  tb, 0, stream>>>(Wg,  Wgt,  512,  1536);
  // phase A: input branches 0+1 in one launch (fills 256 CUs)
  {
    GCfg c0 = { deterB, 4096, 4096, W0t, 4096, yB, 4096 };
    GCfg c1 = { stochB, 1024, 1024, W1t, 1024, yB + 512, 4096 };
    gemm_branch2<<<dim3(4, 32, 2), b256, 0, stream>>>(c0, c1);
  }
  branch23_k<<<dim3(4096, 2), b256, 0, stream>>>(action, demb, W2, b2, g2, W3, b3, g3, xB);
  epi_branch_k<<<dim3(4096, 2), b256, 0, stream>>>(yB, b0, g0, b1, g1, xB);
  // hidden block layer 0: [deter_blk | x] @ Wh0
  gemm_bf16<<<dim3(4, 32, 8), b256, 0, stream>>>(deterB, 4096, 512, 512, xB, 2048, 2048,
                                                 Wh0t, 2560, 512LL * 2560, yB, 4096, 512);
  epi_full_k<<<dim3(4096), b256, 0, stream>>>(yB, bh0, gh0, hB);
  // hidden block layer 1
  gemm_bf16<<<dim3(4, 32, 8), b256, 0, stream>>>(hB, 4096, 512, 512, nullptr, 0, 0,
                                                 Wh1t, 512, 512LL * 512, yB, 4096, 512);
  epi_full_k<<<dim3(4096), b256, 0, stream>>>(yB, bh1, gh1, hB);
  // GRU gates block GEMM -> gates buffer (bf16)
  gemm_bf16<<<dim3(12, 32, 8), b256, 0, stream>>>(hB, 4096, 512, 512, nullptr, 0, 0,
                                                  Wgt, 512, 1536LL * 512, gatesB, 12288, 1536);
  final_k<<<dim3(8192), b256, 0, stream>>>(gatesB, bg, deter, out);
}

// Round 4
// 450.105 us; speedup vs baseline: 1.3500x; 1.3199x over previous
//
#include <hip/hip_runtime.h>
#include <hip/hip_bf16.h>
#include <cstdint>

typedef __bf16 bf16x8 __attribute__((ext_vector_type(8)));
typedef float f32x4 __attribute__((ext_vector_type(4)));
typedef unsigned short u16x8 __attribute__((ext_vector_type(8)));
typedef unsigned short u16x4 __attribute__((ext_vector_type(4)));

__device__ __forceinline__ unsigned short f2bf(float f) {
  unsigned int u = __float_as_uint(f);
  u += 0x7FFFu + ((u >> 16) & 1u);
  return (unsigned short)(u >> 16);
}
__device__ __forceinline__ float bf2f(unsigned short h) {
  return __uint_as_float(((unsigned int)h) << 16);
}
__device__ __forceinline__ float sigmoidf_(float x) { return 1.f / (1.f + __expf(-x)); }
__device__ __forceinline__ float siluf_(float x) { return x * sigmoidf_(x); }

#define GLOAD_LDS16(gsrc, ldst) \
  __builtin_amdgcn_global_load_lds((const __attribute__((address_space(1))) void*)(gsrc), \
                                   (__attribute__((address_space(3))) void*)(ldst), 16, 0, 0)

#define S_BARRIER() asm volatile("s_barrier" ::: "memory")
#define WAIT_LGKM0() do { asm volatile("s_waitcnt lgkmcnt(0)" ::: "memory"); \
                          __builtin_amdgcn_sched_barrier(0); } while (0)

// ---------------------------------------------------------------------------
// Phased GEMM core. 256x256 tile, BK=32, 8 waves (2M x 4N), 512 threads.
// 3 LDS buffers, 2-tile prefetch lookahead, counted vmcnt(4) (never 0 in
// steady state). LDS XOR-swizzle o^=((o>>7)&3)<<4 applied on BOTH the
// global_load_lds source coords and the ds_read addresses (rule #21).
// vmcnt accounting: prologue leaves 8 outstanding, vmcnt(4) vouches tile T;
// steady state: phase0 +2 (stageA T+2), phase1 +2 (stageB T+2) then vmcnt(4)
// retires tile T+1's 4 loads before the barrier every wave passes.
// ---------------------------------------------------------------------------
template<int F32>
__device__ __forceinline__ void gemm8_core(
    const unsigned short* __restrict__ A1, int lda1, int K1,
    const unsigned short* __restrict__ A2, int lda2, int K2,
    const unsigned short* __restrict__ Bt, int ldb,
    void* __restrict__ C, int ldc,
    int tm, int tn, unsigned short* lds)
{
  const int tid = threadIdx.x;
  const int lane = tid & 63;
  const int wave = tid >> 6;                 // 0..7
  const int wm = (wave >> 2) * 128;          // 0 / 128
  const int wn = (wave & 3) * 64;            // 0..192
  const int frow = lane & 15;
  const int chunk16 = (lane >> 4) * 16;      // byte offset of k-chunk
  const int nt = (K1 + K2) >> 5;

  // stage one 256x32 operand tile (16KB region): 2 gload_lds per thread.
  // dest is linear (wave base + lane*16); source coord = swz(dest offset).
  auto stageA = [&](unsigned short* dstA, int ktBase) {
    const unsigned short* Ab; int alda, kloc;
    if (ktBase >= K1) { Ab = A2; alda = lda2; kloc = ktBase - K1; }
    else              { Ab = A1; alda = lda1; kloc = ktBase; }
#pragma unroll
    for (int j = 0; j < 2; ++j) {
      int o = j * 8192 + tid * 16;           // linear dest byte offset
      int so = o ^ (((o >> 7) & 3) << 4);    // swizzled source coord
      int row = so >> 6, cb = so & 63;
      GLOAD_LDS16(Ab + (long long)(tm + row) * alda + kloc + (cb >> 1),
                  (char*)dstA + j * 8192 + wave * 1024);
    }
  };
  auto stageB = [&](unsigned short* dstB, int ktBase) {
#pragma unroll
    for (int j = 0; j < 2; ++j) {
      int o = j * 8192 + tid * 16;
      int so = o ^ (((o >> 7) & 3) << 4);
      int row = so >> 6, cb = so & 63;
      GLOAD_LDS16(Bt + (long long)(tn + row) * ldb + ktBase + (cb >> 1),
                  (char*)dstB + j * 8192 + wave * 1024);
    }
  };
  auto ldswz = [&](const unsigned short* rg, int row) -> bf16x8 {
    int o = row * 64 + chunk16;
    o ^= ((o >> 7) & 3) << 4;
    return *(const bf16x8*)((const char*)rg + o);
  };

  f32x4 acc[8][4] = {};

  unsigned short* pc = lds;                  // tile T
  unsigned short* pn = lds + 16384;          // tile T+1
  unsigned short* pf = lds + 32768;          // staging dest (T+2)

  // prologue: stage tile0 + tile1, wait tile0 (tile1's 4 loads in flight)
  stageA(pc, 0); stageB(pc + 8192, 0);
  stageA(pn, 32); stageB(pn + 8192, 32);
  asm volatile("s_waitcnt vmcnt(4)" ::: "memory");
  S_BARRIER();

  for (int T = 0; T < nt; ++T) {
    const unsigned short* A_ = pc;
    const unsigned short* B_ = pc + 8192;
    bf16x8 av[4], bv[4];
    // ---- phase 0: B frags + A quad0 (m-frags 0..3) ----
#pragma unroll
    for (int j = 0; j < 4; ++j) bv[j] = ldswz(B_, wn + j * 16 + frow);
#pragma unroll
    for (int i = 0; i < 4; ++i) av[i] = ldswz(A_, wm + i * 16 + frow);
    if (T + 2 < nt) stageA(pf, (T + 2) * 32);
    S_BARRIER();
    WAIT_LGKM0();
    __builtin_amdgcn_s_setprio(1);
#pragma unroll
    for (int i = 0; i < 4; ++i)
#pragma unroll
      for (int j = 0; j < 4; ++j)
        acc[i][j] = __builtin_amdgcn_mfma_f32_16x16x32_bf16(av[i], bv[j], acc[i][j], 0, 0, 0);
    __builtin_amdgcn_s_setprio(0);
    __builtin_amdgcn_sched_barrier(0);
    S_BARRIER();
    // ---- phase 1: A quad1 (m-frags 4..7) ----
#pragma unroll
    for (int i = 0; i < 4; ++i) av[i] = ldswz(A_, wm + 64 + i * 16 + frow);
    if (T + 2 < nt) {
      stageB(pf + 8192, (T + 2) * 32);
      asm volatile("s_waitcnt vmcnt(4)" ::: "memory");  // T+1 landed; T+2 in flight
    } else if (T + 1 < nt) {
      asm volatile("s_waitcnt vmcnt(0)" ::: "memory");  // tail drain
    }
    S_BARRIER();
    WAIT_LGKM0();
    __builtin_amdgcn_s_setprio(1);
#pragma unroll
    for (int i = 0; i < 4; ++i)
#pragma unroll
      for (int j = 0; j < 4; ++j)
        acc[4 + i][j] = __builtin_amdgcn_mfma_f32_16x16x32_bf16(av[i], bv[j], acc[4 + i][j], 0, 0, 0);
    __builtin_amdgcn_s_setprio(0);
    __builtin_amdgcn_sched_barrier(0);
    S_BARRIER();
    // rotate buffers
    unsigned short* t = pc; pc = pn; pn = pf; pf = t;
  }

  // epilogue: C/D layout col=lane&15, row=(lane>>4)*4+i
  const int cr = (lane >> 4) * 4;
  const int cc = lane & 15;
#pragma unroll
  for (int mf = 0; mf < 8; ++mf) {
    const int r0 = tm + wm + mf * 16 + cr;
#pragma unroll
    for (int j = 0; j < 4; ++j) {
      const int col = tn + wn + j * 16 + cc;
#pragma unroll
      for (int i = 0; i < 4; ++i) {
        if (F32) ((float*)C)[(long long)(r0 + i) * ldc + col] = acc[mf][j][i];
        else ((unsigned short*)C)[(long long)(r0 + i) * ldc + col] = f2bf(acc[mf][j][i]);
      }
    }
  }
}

// Batched (z = group) two-segment GEMM, bf16 output.
__global__ __launch_bounds__(512, 2) void gemm8(
    const unsigned short* __restrict__ A1, int lda1, long long a1_bs, int K1,
    const unsigned short* __restrict__ A2, int lda2, int K2,
    const unsigned short* __restrict__ Bt, int ldb, long long bt_bs,
    unsigned short* __restrict__ C, int ldc, long long c_bs)
{
  __shared__ unsigned short lds[3 * 16384];
  const int g = blockIdx.z;
  gemm8_core<0>(A1 + (long long)g * a1_bs, lda1, K1, A2, lda2, K2,
                Bt + (long long)g * bt_bs, ldb,
                C + (long long)g * c_bs, ldc,
                blockIdx.y * 256, blockIdx.x * 256, lds);
}

// Branch pack: z selects one of 5 configs (4x split-K of branch0 + branch1),
// f32 partial output.
struct BCfg { const unsigned short* A; int lda; const unsigned short* Bt; int ldb; float* C; };
struct BPack { BCfg c[5]; };
__global__ __launch_bounds__(512, 2) void gemm8_branch(BPack p) {
  __shared__ unsigned short lds[3 * 16384];
  BCfg c = p.c[blockIdx.z];
  gemm8_core<1>(c.A, c.lda, 1024, nullptr, 0, 0, c.Bt, c.ldb, c.C, 512,
                blockIdx.y * 256, blockIdx.x * 256, lds);
}

// ---------------------------------------------------------------------------
// fp32 -> bf16 cast for two buffers in one launch (4 elems / thread)
// ---------------------------------------------------------------------------
__global__ void cvt2_bf16_k(const float* __restrict__ sa, unsigned short* __restrict__ da, int n4a,
                            const float* __restrict__ sb, unsigned short* __restrict__ db, int n4b) {
  int i = blockIdx.x * 256 + threadIdx.x;
  const float* s; unsigned short* d;
  if (i < n4a) { s = sa; d = da; }
  else { i -= n4a; if (i >= n4b) return; s = sb; d = db; }
  float4 v = ((const float4*)s)[i];
  u16x4 o;
  o.x = f2bf(v.x); o.y = f2bf(v.y); o.z = f2bf(v.z); o.w = f2bf(v.w);
  ((u16x4*)d)[i] = o;
}

// ---------------------------------------------------------------------------
// Batched transpose + cast: src fp32 [z][R][C] -> dst bf16 [z][C][R]
// ---------------------------------------------------------------------------
__global__ void transpose_cvt(const float* __restrict__ src, unsigned short* __restrict__ dst,
                              int R, int C) {
  __shared__ float t[32][33];
  const long long bOff = (long long)blockIdx.z * R * C;
  src += bOff; dst += bOff;
  const int c0 = blockIdx.x * 32, r0 = blockIdx.y * 32;
  const int tx = threadIdx.x, ty = threadIdx.y;  // (32,8)
#pragma unroll
  for (int i = 0; i < 4; ++i) {
    int r = r0 + ty + i * 8, c = c0 + tx;
    if (r < R && c < C) t[ty + i * 8][tx] = src[(long long)r * C + c];
  }
  __syncthreads();
#pragma unroll
  for (int i = 0; i < 4; ++i) {
    int c = c0 + ty + i * 8, r = r0 + tx;
    if (r < R && c < C) dst[(long long)c * R + r] = f2bf(t[tx][ty + i * 8]);
  }
}

// ---------------------------------------------------------------------------
// Branches 2 (action, K=32, normalized) and 3 (d_emb, K=16): tiny-K GEMM
// fused with RMSNorm(512)+SiLU, writes x cols [1024..2047] bf16.
// ---------------------------------------------------------------------------
__global__ __launch_bounds__(256) void branch23_k(
    const float* __restrict__ action, const float* __restrict__ demb,
    const float* __restrict__ W2, const float* __restrict__ b2, const float* __restrict__ g2,
    const float* __restrict__ W3, const float* __restrict__ b3, const float* __restrict__ g3,
    unsigned short* __restrict__ x)
{
  const int row = blockIdx.x, br = blockIdx.y;
  const int K = br ? 16 : 32;
  const float* W  = br ? W3 : W2;
  const float* bb = br ? b3 : b2;
  const float* gg = br ? g3 : g2;
  __shared__ float a[32];
  __shared__ float red[4];
  const int tid = threadIdx.x, lane = tid & 63, wave = tid >> 6;
  if (tid < K) {
    float t = br ? demb[(long long)row * 16 + tid] : action[(long long)row * 32 + tid];
    if (!br) t = t / fmaxf(fabsf(t), 1.f);
    a[tid] = t;
  }
  __syncthreads();
  float y0 = bb[tid], y1 = bb[tid + 256];
  for (int k = 0; k < K; ++k) {
    float av = a[k];
    y0 += av * W[k * 512 + tid];
    y1 += av * W[k * 512 + tid + 256];
  }
  float ss = y0 * y0 + y1 * y1;
  for (int o = 32; o > 0; o >>= 1) ss += __shfl_xor(ss, o);
  if (lane == 0) red[wave] = ss;
  __syncthreads();
  float ms = (red[0] + red[1] + red[2] + red[3]) * (1.f / 512.f);
  float sc = rsqrtf(ms + 1e-4f);
  unsigned short* xr = x + (long long)row * 2048 + 1024 + br * 512;
  xr[tid]       = f2bf(siluf_(y0 * sc * gg[tid]));
  xr[tid + 256] = f2bf(siluf_(y1 * sc * gg[tid + 256]));
}

// ---------------------------------------------------------------------------
// Branch 0/1 epilogue: sum split-K f32 partials + bias -> RMSNorm(512) ->
// SiLU -> x cols [0..1023] bf16.
// ---------------------------------------------------------------------------
__global__ __launch_bounds__(256) void epi_branch_k(
    const float* __restrict__ yP0, const float* __restrict__ yP1,
    const float* __restrict__ b0, const float* __restrict__ g0,
    const float* __restrict__ b1, const float* __restrict__ g1,
    unsigned short* __restrict__ x)
{
  const int row = blockIdx.x, br = blockIdx.y;
  const int tid = threadIdx.x, lane = tid & 63, wave = tid >> 6;
  __shared__ float red[4];
  float v0, v1;
  if (!br) {
    const float* p = yP0 + (long long)row * 512;
    v0 = b0[tid]; v1 = b0[tid + 256];
#pragma unroll
    for (int c = 0; c < 4; ++c) {
      v0 += p[c * 2097152 + tid];
      v1 += p[c * 2097152 + tid + 256];
    }
  } else {
    const float* p = yP1 + (long long)row * 512;
    v0 = b1[tid] + p[tid];
    v1 = b1[tid + 256] + p[tid + 256];
  }
  const float* gg = br ? g1 : g0;
  float ss = v0 * v0 + v1 * v1;
  for (int o = 32; o > 0; o >>= 1) ss += __shfl_xor(ss, o);
  if (lane == 0) red[wave] = ss;
  __syncthreads();
  float ms = (red[0] + red[1] + red[2] + red[3]) * (1.f / 512.f);
  float sc = rsqrtf(ms + 1e-4f);
  unsigned short* xr = x + (long long)row * 2048 + br * 512;
  xr[tid]       = f2bf(siluf_(v0 * sc * gg[tid]));
  xr[tid + 256] = f2bf(siluf_(v1 * sc * gg[tid + 256]));
}

// ---------------------------------------------------------------------------
// Full-width (4096) epilogue: y(bf16) + bias -> RMSNorm -> SiLU -> h(bf16)
// ---------------------------------------------------------------------------
__global__ __launch_bounds__(256) void epi_full_k(
    const unsigned short* __restrict__ y, const float* __restrict__ bias,
    const float* __restrict__ gw, unsigned short* __restrict__ h)
{
  const int row = blockIdx.x;
  __shared__ float v[4096];
  __shared__ float red[4];
  const int tid = threadIdx.x, lane = tid & 63, wave = tid >> 6;
  const u16x8* yv = (const u16x8*)(y + (long long)row * 4096);
  float ss = 0.f;
#pragma unroll
  for (int j = 0; j < 2; ++j) {
    int vi = j * 256 + tid;
    u16x8 t = yv[vi];
#pragma unroll
    for (int e = 0; e < 8; ++e) {
      float f = bf2f(t[e]) + bias[vi * 8 + e];
      v[vi * 8 + e] = f;
      ss += f * f;
    }
  }
  for (int o = 32; o > 0; o >>= 1) ss += __shfl_xor(ss, o);
  if (lane == 0) red[wave] = ss;
  __syncthreads();
  float ms = (red[0] + red[1] + red[2] + red[3]) * (1.f / 4096.f);
  float sc = rsqrtf(ms + 1e-4f);
  u16x8* hv = (u16x8*)(h + (long long)row * 4096);
#pragma unroll
  for (int j = 0; j < 2; ++j) {
    int vi = j * 256 + tid;
    u16x8 o8;
#pragma unroll
    for (int e = 0; e < 8; ++e) {
      float t = v[vi * 8 + e] * sc * gw[vi * 8 + e];
      o8[e] = f2bf(siluf_(t));
    }
    hv[vi] = o8;
  }
}

// ---------------------------------------------------------------------------
// Final: gates(bf16) + bg -> GRU combine with original deter -> out fp32
// ---------------------------------------------------------------------------
__global__ __launch_bounds__(256) void final_k(
    const unsigned short* __restrict__ gates, const float* __restrict__ bg,
    const float* __restrict__ deter, float* __restrict__ out)
{
  const long long idx = ((long long)blockIdx.x * 256 + threadIdx.x) * 8;
  const int c = (int)(idx & 4095);
  const int r = (int)(idx >> 12);
  const int g = c >> 9, o = c & 511;
  const long long gbase = (long long)r * 12288 + g * 1536 + o;
  u16x8 rs = *(const u16x8*)&gates[gbase];
  u16x8 cd = *(const u16x8*)&gates[gbase + 512];
  u16x8 up = *(const u16x8*)&gates[gbase + 1024];
  const float* bgp = bg + g * 1536 + o;
  float4 d0 = *(const float4*)&deter[idx];
  float4 d1 = *(const float4*)&deter[idx + 4];
  float dv[8] = {d0.x, d0.y, d0.z, d0.w, d1.x, d1.y, d1.z, d1.w};
  float ov[8];
#pragma unroll
  for (int j = 0; j < 8; ++j) {
    float reset = sigmoidf_(bf2f(rs[j]) + bgp[j]);
    float cand  = tanhf(reset * (bf2f(cd[j]) + bgp[512 + j]));
    float upd   = sigmoidf_(bf2f(up[j]) + bgp[1024 + j] - 1.f);
    ov[j] = upd * cand + (1.f - upd) * dv[j];
  }
  *(float4*)&out[idx]     = make_float4(ov[0], ov[1], ov[2], ov[3]);
  *(float4*)&out[idx + 4] = make_float4(ov[4], ov[5], ov[6], ov[7]);
}

// ---------------------------------------------------------------------------
extern "C" void kernel_launch(void* const* d_in, const int* in_sizes, int n_in,
                              void* d_out, int out_size, void* d_ws, size_t ws_size,
                              hipStream_t stream) {
  const float* stoch  = (const float*)d_in[0];
  const float* deter  = (const float*)d_in[1];
  const float* action = (const float*)d_in[2];
  const float* demb   = (const float*)d_in[3];
  const float* W0 = (const float*)d_in[4];
  const float* b0 = (const float*)d_in[5];
  const float* g0 = (const float*)d_in[6];
  const float* W1 = (const float*)d_in[7];
  const float* b1 = (const float*)d_in[8];
  const float* g1 = (const float*)d_in[9];
  const float* W2 = (const float*)d_in[10];
  const float* b2 = (const float*)d_in[11];
  const float* g2 = (const float*)d_in[12];
  const float* W3 = (const float*)d_in[13];
  const float* b3 = (const float*)d_in[14];
  const float* g3 = (const float*)d_in[15];
  const float* Wh0 = (const float*)d_in[16];
  const float* bh0 = (const float*)d_in[17];
  const float* gh0 = (const float*)d_in[18];
  const float* Wh1 = (const float*)d_in[19];
  const float* bh1 = (const float*)d_in[20];
  const float* gh1 = (const float*)d_in[21];
  const float* Wg  = (const float*)d_in[22];
  const float* bg  = (const float*)d_in[23];
  float* out = (float*)d_out;

  // workspace layout (bytes); aggressive overlap of dead buffers:
  //   deterB dead after hidden0 -> Wgt transposed into @0 afterwards
  //   yP0/yP1 dead after epi_branch -> yB reuses @63963136
  //   gatesB overlaps [stochB..Wh1t] region, all dead before gates GEMM
  char* ws = (char*)d_ws;
  unsigned short* deterB = (unsigned short*)(ws + 0);          // 33.55 MB
  unsigned short* Wgt    = (unsigned short*)(ws + 0);          // 12.58 MB (late)
  unsigned short* stochB = (unsigned short*)(ws + 33554432);   //  8.39 MB
  unsigned short* gatesB = (unsigned short*)(ws + 33554432);   // 100.66 MB (late)
  unsigned short* W0t    = (unsigned short*)(ws + 41943040);   //  4.19 MB
  unsigned short* W1t    = (unsigned short*)(ws + 46137344);   //  1.05 MB
  unsigned short* xB     = (unsigned short*)(ws + 47185920);   // 16.78 MB
  float*          yP0    = (float*)(ws + 63963136);            // 33.55 MB (early)
  unsigned short* yB     = (unsigned short*)(ws + 63963136);   // 33.55 MB (late)
  float*          yP1    = (float*)(ws + 97517568);            //  8.39 MB
  unsigned short* Wh0t   = (unsigned short*)(ws + 105906176);  // 20.97 MB
  unsigned short* Wh1t   = (unsigned short*)(ws + 126877696);  //  4.19 MB
  unsigned short* hB     = (unsigned short*)(ws + 134217728);  // 33.55 MB -> ends 167.8MB
  (void)in_sizes; (void)n_in; (void)out_size; (void)ws_size;

  dim3 b256(256);
  dim3 b512(512);
  dim3 tb(32, 8);
  // input casts + early weight transposes
  cvt2_bf16_k<<<dim3(20480), b256, 0, stream>>>(deter, deterB, 4194304,
                                                stoch, stochB, 1048576);
  transpose_cvt<<<dim3(16, 128, 1), tb, 0, stream>>>(W0,  W0t,  4096, 512);
  transpose_cvt<<<dim3(16, 32, 1),  tb, 0, stream>>>(W1,  W1t,  1024, 512);
  // branches 0+1: split-K x4 for branch0 (K=4096 -> 4 x 1024) + branch1
  {
    BPack p;
    for (int z = 0; z < 4; ++z)
      p.c[z] = { deterB + z * 1024, 4096, W0t + z * 1024, 4096, yP0 + (long long)z * 2097152 };
    p.c[4] = { stochB, 1024, W1t, 1024, yP1 };
    gemm8_branch<<<dim3(2, 16, 5), b512, 0, stream>>>(p);
  }
  branch23_k<<<dim3(4096, 2), b256, 0, stream>>>(action, demb, W2, b2, g2, W3, b3, g3, xB);
  epi_branch_k<<<dim3(4096, 2), b256, 0, stream>>>(yP0, yP1, b0, g0, b1, g1, xB);
  // hidden block layer 0: [deter_blk | x] @ Wh0   (N=512 -> grid.x = 2)
  transpose_cvt<<<dim3(16, 80, 8),  tb, 0, stream>>>(Wh0, Wh0t, 2560, 512);
  transpose_cvt<<<dim3(16, 16, 8),  tb, 0, stream>>>(Wh1, Wh1t, 512,  512);
  gemm8<<<dim3(2, 16, 8), b512, 0, stream>>>(deterB, 4096, 512, 512, xB, 2048, 2048,
                                             Wh0t, 2560, 512LL * 2560, yB, 4096, 512);
  // Wgt transpose after hidden0 (reuses deterB space)
  transpose_cvt<<<dim3(48, 16, 8),  tb, 0, stream>>>(Wg,  Wgt,  512,  1536);
  epi_full_k<<<dim3(4096), b256, 0, stream>>>(yB, bh0, gh0, hB);
  // hidden block layer 1   (N=512 -> grid.x = 2)
  gemm8<<<dim3(2, 16, 8), b512, 0, stream>>>(hB, 4096, 512, 512, nullptr, 0, 0,
                                             Wh1t, 512, 512LL * 512, yB, 4096, 512);
  epi_full_k<<<dim3(4096), b256, 0, stream>>>(yB, bh1, gh1, hB);
  // GRU gates block GEMM -> gates buffer (bf16)   (N=1536 -> grid.x = 6)
  gemm8<<<dim3(6, 16, 8), b512, 0, stream>>>(hB, 4096, 512, 512, nullptr, 0, 0,
                                             Wgt, 512, 1536LL * 512, gatesB, 12288, 1536);
  final_k<<<dim3(8192), b256, 0, stream>>>(gatesB, bg, deter, out);
}

// Round 5
// 352.736 us; speedup vs baseline: 1.7227x; 1.2760x over previous
//
#include <hip/hip_runtime.h>
#include <hip/hip_bf16.h>
#include <cstdint>

typedef __bf16 bf16x8 __attribute__((ext_vector_type(8)));
typedef float f32x4 __attribute__((ext_vector_type(4)));
typedef unsigned short u16x8 __attribute__((ext_vector_type(8)));
typedef unsigned short u16x4 __attribute__((ext_vector_type(4)));

__device__ __forceinline__ unsigned short f2bf(float f) {
  unsigned int u = __float_as_uint(f);
  u += 0x7FFFu + ((u >> 16) & 1u);
  return (unsigned short)(u >> 16);
}
__device__ __forceinline__ float bf2f(unsigned short h) {
  return __uint_as_float(((unsigned int)h) << 16);
}
__device__ __forceinline__ float frcp_(float x) { return __builtin_amdgcn_rcpf(x); }
__device__ __forceinline__ float sigmoid_fast(float x) { return frcp_(1.f + __expf(-x)); }
__device__ __forceinline__ float tanh_fast(float x) { return 1.f - 2.f * frcp_(__expf(2.f * x) + 1.f); }
__device__ __forceinline__ float siluf_(float x) { return x * sigmoid_fast(x); }

#define GLOAD_LDS16(gsrc, ldst) \
  __builtin_amdgcn_global_load_lds((const __attribute__((address_space(1))) void*)(gsrc), \
                                   (__attribute__((address_space(3))) void*)(ldst), 16, 0, 0)

#define S_BARRIER() asm volatile("s_barrier" ::: "memory")
#define WAIT_LGKM0() do { asm volatile("s_waitcnt lgkmcnt(0)" ::: "memory"); \
                          __builtin_amdgcn_sched_barrier(0); } while (0)

// ---------------------------------------------------------------------------
// Phased GEMM core. 256x256 tile, BK=32, 8 waves (2M x 4N), 512 threads.
// 3 LDS buffers, 2-tile lookahead, counted vmcnt(4). XOR-swizzle
// o^=((o>>7)&3)<<4 on BOTH gload source coords and ds_read addrs.
// ---------------------------------------------------------------------------
template<int F32>
__device__ __forceinline__ void gemm8_core(
    const unsigned short* __restrict__ A1, int lda1, int K1,
    const unsigned short* __restrict__ A2, int lda2, int K2,
    const unsigned short* __restrict__ Bt, int ldb,
    void* __restrict__ C, int ldc,
    int tm, int tn, unsigned short* lds)
{
  const int tid = threadIdx.x;
  const int lane = tid & 63;
  const int wave = tid >> 6;                 // 0..7
  const int wm = (wave >> 2) * 128;          // 0 / 128
  const int wn = (wave & 3) * 64;            // 0..192
  const int frow = lane & 15;
  const int chunk16 = (lane >> 4) * 16;      // byte offset of k-chunk
  const int nt = (K1 + K2) >> 5;

  auto stageA = [&](unsigned short* dstA, int ktBase) {
    const unsigned short* Ab; int alda, kloc;
    if (ktBase >= K1) { Ab = A2; alda = lda2; kloc = ktBase - K1; }
    else              { Ab = A1; alda = lda1; kloc = ktBase; }
#pragma unroll
    for (int j = 0; j < 2; ++j) {
      int o = j * 8192 + tid * 16;
      int so = o ^ (((o >> 7) & 3) << 4);
      int row = so >> 6, cb = so & 63;
      GLOAD_LDS16(Ab + (long long)(tm + row) * alda + kloc + (cb >> 1),
                  (char*)dstA + j * 8192 + wave * 1024);
    }
  };
  auto stageB = [&](unsigned short* dstB, int ktBase) {
#pragma unroll
    for (int j = 0; j < 2; ++j) {
      int o = j * 8192 + tid * 16;
      int so = o ^ (((o >> 7) & 3) << 4);
      int row = so >> 6, cb = so & 63;
      GLOAD_LDS16(Bt + (long long)(tn + row) * ldb + ktBase + (cb >> 1),
                  (char*)dstB + j * 8192 + wave * 1024);
    }
  };
  auto ldswz = [&](const unsigned short* rg, int row) -> bf16x8 {
    int o = row * 64 + chunk16;
    o ^= ((o >> 7) & 3) << 4;
    return *(const bf16x8*)((const char*)rg + o);
  };

  f32x4 acc[8][4] = {};

  unsigned short* pc = lds;
  unsigned short* pn = lds + 16384;
  unsigned short* pf = lds + 32768;

  stageA(pc, 0); stageB(pc + 8192, 0);
  stageA(pn, 32); stageB(pn + 8192, 32);
  asm volatile("s_waitcnt vmcnt(4)" ::: "memory");
  S_BARRIER();

  for (int T = 0; T < nt; ++T) {
    const unsigned short* A_ = pc;
    const unsigned short* B_ = pc + 8192;
    bf16x8 av[4], bv[4];
#pragma unroll
    for (int j = 0; j < 4; ++j) bv[j] = ldswz(B_, wn + j * 16 + frow);
#pragma unroll
    for (int i = 0; i < 4; ++i) av[i] = ldswz(A_, wm + i * 16 + frow);
    if (T + 2 < nt) stageA(pf, (T + 2) * 32);
    S_BARRIER();
    WAIT_LGKM0();
    __builtin_amdgcn_s_setprio(1);
#pragma unroll
    for (int i = 0; i < 4; ++i)
#pragma unroll
      for (int j = 0; j < 4; ++j)
        acc[i][j] = __builtin_amdgcn_mfma_f32_16x16x32_bf16(av[i], bv[j], acc[i][j], 0, 0, 0);
    __builtin_amdgcn_s_setprio(0);
    __builtin_amdgcn_sched_barrier(0);
    S_BARRIER();
#pragma unroll
    for (int i = 0; i < 4; ++i) av[i] = ldswz(A_, wm + 64 + i * 16 + frow);
    if (T + 2 < nt) {
      stageB(pf + 8192, (T + 2) * 32);
      asm volatile("s_waitcnt vmcnt(4)" ::: "memory");
    } else if (T + 1 < nt) {
      asm volatile("s_waitcnt vmcnt(0)" ::: "memory");
    }
    S_BARRIER();
    WAIT_LGKM0();
    __builtin_amdgcn_s_setprio(1);
#pragma unroll
    for (int i = 0; i < 4; ++i)
#pragma unroll
      for (int j = 0; j < 4; ++j)
        acc[4 + i][j] = __builtin_amdgcn_mfma_f32_16x16x32_bf16(av[i], bv[j], acc[4 + i][j], 0, 0, 0);
    __builtin_amdgcn_s_setprio(0);
    __builtin_amdgcn_sched_barrier(0);
    S_BARRIER();
    unsigned short* t = pc; pc = pn; pn = pf; pf = t;
  }

  const int cr = (lane >> 4) * 4;
  const int cc = lane & 15;
#pragma unroll
  for (int mf = 0; mf < 8; ++mf) {
    const int r0 = tm + wm + mf * 16 + cr;
#pragma unroll
    for (int j = 0; j < 4; ++j) {
      const int col = tn + wn + j * 16 + cc;
#pragma unroll
      for (int i = 0; i < 4; ++i) {
        if (F32) ((float*)C)[(long long)(r0 + i) * ldc + col] = acc[mf][j][i];
        else ((unsigned short*)C)[(long long)(r0 + i) * ldc + col] = f2bf(acc[mf][j][i]);
      }
    }
  }
}

// Batched (z = group) two-segment GEMM, bf16 output.
__global__ __launch_bounds__(512, 2) void gemm8(
    const unsigned short* __restrict__ A1, int lda1, long long a1_bs, int K1,
    const unsigned short* __restrict__ A2, int lda2, int K2,
    const unsigned short* __restrict__ Bt, int ldb, long long bt_bs,
    unsigned short* __restrict__ C, int ldc, long long c_bs)
{
  __shared__ unsigned short lds[3 * 16384];
  const int g = blockIdx.z;
  gemm8_core<0>(A1 + (long long)g * a1_bs, lda1, K1, A2, lda2, K2,
                Bt + (long long)g * bt_bs, ldb,
                C + (long long)g * c_bs, ldc,
                blockIdx.y * 256, blockIdx.x * 256, lds);
}

// Branch pack: z selects one of 5 configs (4x split-K of branch0 + branch1)
struct BCfg { const unsigned short* A; int lda; const unsigned short* Bt; int ldb; float* C; };
struct BPack { BCfg c[5]; };
__global__ __launch_bounds__(512, 2) void gemm8_branch(BPack p) {
  __shared__ unsigned short lds[3 * 16384];
  BCfg c = p.c[blockIdx.z];
  gemm8_core<1>(c.A, c.lda, 1024, nullptr, 0, 0, c.Bt, c.ldb, c.C, 512,
                blockIdx.y * 256, blockIdx.x * 256, lds);
}

// ---------------------------------------------------------------------------
// Fused gates GEMM + GRU combine. Tile 256M x 192N(nn), BK=32, 8 waves
// (2 M-halves x 4 N-stripes of 48). Wgt columns pre-permuted so
// nn = (o>>4)*48 + gate*16 + (o&15): each wave's 48-stripe holds all 3
// gates for one 16-wide o-range -> reset/cand/update land in-register.
// Same 3-buffer counted-vmcnt schedule; B-stage is 1.5 loads/thread so
// vmcnt constants differ per wave half (4 for waves 0-3, 3 for 4-7).
// ---------------------------------------------------------------------------
__global__ __launch_bounds__(512, 2) void gemm_gru(
    const unsigned short* __restrict__ hB,    // [4096][4096] bf16
    const unsigned short* __restrict__ Wgt,   // [8][1536 nn][512] bf16
    const float* __restrict__ bg,
    const float* __restrict__ deter,
    float* __restrict__ out)
{
  __shared__ unsigned short lds[3 * 14336];   // per buf: A 16KB + B 12KB
  const int g = blockIdx.z;
  const int tm = blockIdx.y * 256;
  const int tn = blockIdx.x * 192;
  const unsigned short* A  = hB + g * 512;
  const unsigned short* Bt = Wgt + (long long)g * 1536 * 512;
  const int tid = threadIdx.x, lane = tid & 63, wave = tid >> 6;
  const int wm = (wave >> 2) * 128;
  const int wv = wave & 3;
  const int frow = lane & 15, chunk16 = (lane >> 4) * 16;
  const bool wlow = (wave < 4);
  const int nt = 16;                          // K=512 / 32

  auto stageA = [&](unsigned short* buf, int kt) {
#pragma unroll
    for (int j = 0; j < 2; ++j) {
      int o = j * 8192 + tid * 16;
      int so = o ^ (((o >> 7) & 3) << 4);
      int row = so >> 6, cb = so & 63;
      GLOAD_LDS16(A + (long long)(tm + row) * 4096 + kt + (cb >> 1),
                  (char*)buf + j * 8192 + wave * 1024);
    }
  };
  auto stageB = [&](unsigned short* buf, int kt) {
    char* bb = (char*)(buf + 8192);
    {
      int o = tid * 16;
      int so = o ^ (((o >> 7) & 3) << 4);
      int row = so >> 6, cb = so & 63;
      GLOAD_LDS16(Bt + (long long)(tn + row) * 512 + kt + (cb >> 1),
                  bb + wave * 1024);
    }
    if (tid < 256) {                          // waves 0-3 only (uniform per wave)
      int o = 8192 + tid * 16;
      int so = o ^ (((o >> 7) & 3) << 4);
      int row = so >> 6, cb = so & 63;
      GLOAD_LDS16(Bt + (long long)(tn + row) * 512 + kt + (cb >> 1),
                  bb + 8192 + wave * 1024);
    }
  };
  auto ldA = [&](const unsigned short* buf, int row) -> bf16x8 {
    int o = row * 64 + chunk16; o ^= ((o >> 7) & 3) << 4;
    return *(const bf16x8*)((const char*)buf + o);
  };
  auto ldB = [&](const unsigned short* buf, int nf) -> bf16x8 {
    int row = wv * 48 + nf * 16 + frow;
    int o = row * 64 + chunk16; o ^= ((o >> 7) & 3) << 4;
    return *(const bf16x8*)((const char*)(buf + 8192) + o);
  };
  auto wait_pref = [&]() {
    if (wlow) asm volatile("s_waitcnt vmcnt(4)" ::: "memory");
    else      asm volatile("s_waitcnt vmcnt(3)" ::: "memory");
  };

  f32x4 acc[8][3] = {};

  unsigned short* pc = lds;
  unsigned short* pn = lds + 14336;
  unsigned short* pf = lds + 28672;

  stageA(pc, 0); stageB(pc, 0);
  stageA(pn, 32); stageB(pn, 32);
  wait_pref();
  S_BARRIER();

  for (int T = 0; T < nt; ++T) {
    bf16x8 av[4], bv[3];
#pragma unroll
    for (int j = 0; j < 3; ++j) bv[j] = ldB(pc, j);
#pragma unroll
    for (int i = 0; i < 4; ++i) av[i] = ldA(pc, wm + i * 16 + frow);
    if (T + 2 < nt) stageA(pf, (T + 2) * 32);
    S_BARRIER();
    WAIT_LGKM0();
    __builtin_amdgcn_s_setprio(1);
#pragma unroll
    for (int i = 0; i < 4; ++i)
#pragma unroll
      for (int j = 0; j < 3; ++j)
        acc[i][j] = __builtin_amdgcn_mfma_f32_16x16x32_bf16(av[i], bv[j], acc[i][j], 0, 0, 0);
    __builtin_amdgcn_s_setprio(0);
    __builtin_amdgcn_sched_barrier(0);
    S_BARRIER();
#pragma unroll
    for (int i = 0; i < 4; ++i) av[i] = ldA(pc, wm + 64 + i * 16 + frow);
    if (T + 2 < nt) {
      stageB(pf, (T + 2) * 32);
      wait_pref();
    } else if (T + 1 < nt) {
      asm volatile("s_waitcnt vmcnt(0)" ::: "memory");
    }
    S_BARRIER();
    WAIT_LGKM0();
    __builtin_amdgcn_s_setprio(1);
#pragma unroll
    for (int i = 0; i < 4; ++i)
#pragma unroll
      for (int j = 0; j < 3; ++j)
        acc[4 + i][j] = __builtin_amdgcn_mfma_f32_16x16x32_bf16(av[i], bv[j], acc[4 + i][j], 0, 0, 0);
    __builtin_amdgcn_s_setprio(0);
    __builtin_amdgcn_sched_barrier(0);
    S_BARRIER();
    unsigned short* t = pc; pc = pn; pn = pf; pf = t;
  }

  // GRU combine epilogue: lane holds reset/cand/update for (r, o_col)
  const int cr = (lane >> 4) * 4, cc = lane & 15;
  const int o_col = (blockIdx.x * 4 + wv) * 16 + cc;
  const int gcol = g * 512 + o_col;
  const float bgr = bg[g * 1536 + o_col];
  const float bgc = bg[g * 1536 + 512 + o_col];
  const float bgu = bg[g * 1536 + 1024 + o_col];
#pragma unroll
  for (int mf = 0; mf < 8; ++mf) {
    const int r0 = tm + wm + mf * 16 + cr;
#pragma unroll
    for (int i = 0; i < 4; ++i) {
      const long long off = (long long)(r0 + i) * 4096 + gcol;
      float dt = deter[off];
      float reset = sigmoid_fast(acc[mf][0][i] + bgr);
      float cand  = tanh_fast(reset * (acc[mf][1][i] + bgc));
      float upd   = sigmoid_fast(acc[mf][2][i] + bgu - 1.f);
      out[off] = upd * cand + (1.f - upd) * dt;
    }
  }
}

// ---------------------------------------------------------------------------
// fp32 -> bf16 cast for two buffers in one launch (4 elems / thread)
// ---------------------------------------------------------------------------
__global__ void cvt2_bf16_k(const float* __restrict__ sa, unsigned short* __restrict__ da, int n4a,
                            const float* __restrict__ sb, unsigned short* __restrict__ db, int n4b) {
  int i = blockIdx.x * 256 + threadIdx.x;
  const float* s; unsigned short* d;
  if (i < n4a) { s = sa; d = da; }
  else { i -= n4a; if (i >= n4b) return; s = sb; d = db; }
  float4 v = ((const float4*)s)[i];
  u16x4 o;
  o.x = f2bf(v.x); o.y = f2bf(v.y); o.z = f2bf(v.z); o.w = f2bf(v.w);
  ((u16x4*)d)[i] = o;
}

// ---------------------------------------------------------------------------
// Batched transpose + cast: src fp32 [z][R][C] -> dst bf16 [z][C][R]
// ---------------------------------------------------------------------------
__global__ void transpose_cvt(const float* __restrict__ src, unsigned short* __restrict__ dst,
                              int R, int C) {
  __shared__ float t[32][33];
  const long long bOff = (long long)blockIdx.z * R * C;
  src += bOff; dst += bOff;
  const int c0 = blockIdx.x * 32, r0 = blockIdx.y * 32;
  const int tx = threadIdx.x, ty = threadIdx.y;  // (32,8)
#pragma unroll
  for (int i = 0; i < 4; ++i) {
    int r = r0 + ty + i * 8, c = c0 + tx;
    if (r < R && c < C) t[ty + i * 8][tx] = src[(long long)r * C + c];
  }
  __syncthreads();
#pragma unroll
  for (int i = 0; i < 4; ++i) {
    int c = c0 + ty + i * 8, r = r0 + tx;
    if (r < R && c < C) dst[(long long)c * R + r] = f2bf(t[tx][ty + i * 8]);
  }
}

// ---------------------------------------------------------------------------
// Wg transpose with gate-interleaved row permutation:
// src [8][512][1536] f32, dst [8][1536][512] bf16, row nn = (o>>4)*48+gate*16+(o&15)
// ---------------------------------------------------------------------------
__global__ void transpose_wg(const float* __restrict__ src, unsigned short* __restrict__ dst) {
  __shared__ float t[32][33];
  const int gz = blockIdx.z;
  src += (long long)gz * 512 * 1536;
  dst += (long long)gz * 1536 * 512;
  const int c0 = blockIdx.x * 32, r0 = blockIdx.y * 32;
  const int tx = threadIdx.x, ty = threadIdx.y;  // (32,8)
#pragma unroll
  for (int i = 0; i < 4; ++i)
    t[ty + i * 8][tx] = src[(long long)(r0 + ty + i * 8) * 1536 + c0 + tx];
  __syncthreads();
#pragma unroll
  for (int i = 0; i < 4; ++i) {
    int c = c0 + ty + i * 8;
    int gate = c >> 9, o = c & 511;
    int nn = (o >> 4) * 48 + gate * 16 + (o & 15);
    dst[(long long)nn * 512 + r0 + tx] = f2bf(t[tx][ty + i * 8]);
  }
}

// ---------------------------------------------------------------------------
// Branches 2 (action, K=32, normalized) and 3 (d_emb, K=16): tiny-K GEMM
// fused with RMSNorm(512)+SiLU, writes x cols [1024..2047] bf16.
// ---------------------------------------------------------------------------
__global__ __launch_bounds__(256) void branch23_k(
    const float* __restrict__ action, const float* __restrict__ demb,
    const float* __restrict__ W2, const float* __restrict__ b2, const float* __restrict__ g2,
    const float* __restrict__ W3, const float* __restrict__ b3, const float* __restrict__ g3,
    unsigned short* __restrict__ x)
{
  const int row = blockIdx.x, br = blockIdx.y;
  const int K = br ? 16 : 32;
  const float* W  = br ? W3 : W2;
  const float* bb = br ? b3 : b2;
  const float* gg = br ? g3 : g2;
  __shared__ float a[32];
  __shared__ float red[4];
  const int tid = threadIdx.x, lane = tid & 63, wave = tid >> 6;
  if (tid < K) {
    float t = br ? demb[(long long)row * 16 + tid] : action[(long long)row * 32 + tid];
    if (!br) t = t / fmaxf(fabsf(t), 1.f);
    a[tid] = t;
  }
  __syncthreads();
  float y0 = bb[tid], y1 = bb[tid + 256];
  for (int k = 0; k < K; ++k) {
    float av = a[k];
    y0 += av * W[k * 512 + tid];
    y1 += av * W[k * 512 + tid + 256];
  }
  float ss = y0 * y0 + y1 * y1;
  for (int o = 32; o > 0; o >>= 1) ss += __shfl_xor(ss, o);
  if (lane == 0) red[wave] = ss;
  __syncthreads();
  float ms = (red[0] + red[1] + red[2] + red[3]) * (1.f / 512.f);
  float sc = rsqrtf(ms + 1e-4f);
  unsigned short* xr = x + (long long)row * 2048 + 1024 + br * 512;
  xr[tid]       = f2bf(siluf_(y0 * sc * gg[tid]));
  xr[tid + 256] = f2bf(siluf_(y1 * sc * gg[tid + 256]));
}

// ---------------------------------------------------------------------------
// Branch 0/1 epilogue: sum split-K f32 partials + bias -> RMSNorm(512) ->
// SiLU -> x cols [0..1023] bf16.
// ---------------------------------------------------------------------------
__global__ __launch_bounds__(256) void epi_branch_k(
    const float* __restrict__ yP0, const float* __restrict__ yP1,
    const float* __restrict__ b0, const float* __restrict__ g0,
    const float* __restrict__ b1, const float* __restrict__ g1,
    unsigned short* __restrict__ x)
{
  const int row = blockIdx.x, br = blockIdx.y;
  const int tid = threadIdx.x, lane = tid & 63, wave = tid >> 6;
  __shared__ float red[4];
  float v0, v1;
  if (!br) {
    const float* p = yP0 + (long long)row * 512;
    v0 = b0[tid]; v1 = b0[tid + 256];
#pragma unroll
    for (int c = 0; c < 4; ++c) {
      v0 += p[c * 2097152 + tid];
      v1 += p[c * 2097152 + tid + 256];
    }
  } else {
    const float* p = yP1 + (long long)row * 512;
    v0 = b1[tid] + p[tid];
    v1 = b1[tid + 256] + p[tid + 256];
  }
  const float* gg = br ? g1 : g0;
  float ss = v0 * v0 + v1 * v1;
  for (int o = 32; o > 0; o >>= 1) ss += __shfl_xor(ss, o);
  if (lane == 0) red[wave] = ss;
  __syncthreads();
  float ms = (red[0] + red[1] + red[2] + red[3]) * (1.f / 512.f);
  float sc = rsqrtf(ms + 1e-4f);
  unsigned short* xr = x + (long long)row * 2048 + br * 512;
  xr[tid]       = f2bf(siluf_(v0 * sc * gg[tid]));
  xr[tid + 256] = f2bf(siluf_(v1 * sc * gg[tid + 256]));
}

// ---------------------------------------------------------------------------
// Full-width (4096) epilogue: y(bf16) + bias -> RMSNorm -> SiLU -> h(bf16).
// Register-resident (no LDS round-trip).
// ---------------------------------------------------------------------------
__global__ __launch_bounds__(256) void epi_full_k(
    const unsigned short* __restrict__ y, const float* __restrict__ bias,
    const float* __restrict__ gw, unsigned short* __restrict__ h)
{
  const int row = blockIdx.x;
  __shared__ float red[4];
  const int tid = threadIdx.x, lane = tid & 63, wave = tid >> 6;
  const u16x8* yv = (const u16x8*)(y + (long long)row * 4096);
  u16x8 ta = yv[tid], tb = yv[256 + tid];
  float ba[8], bb8[8];
  *(float4*)&ba[0]  = *(const float4*)&bias[tid * 8];
  *(float4*)&ba[4]  = *(const float4*)&bias[tid * 8 + 4];
  *(float4*)&bb8[0] = *(const float4*)&bias[(256 + tid) * 8];
  *(float4*)&bb8[4] = *(const float4*)&bias[(256 + tid) * 8 + 4];
  float fa[8], fb[8];
  float ss = 0.f;
#pragma unroll
  for (int e = 0; e < 8; ++e) {
    fa[e] = bf2f(ta[e]) + ba[e];  ss += fa[e] * fa[e];
    fb[e] = bf2f(tb[e]) + bb8[e]; ss += fb[e] * fb[e];
  }
  for (int o = 32; o > 0; o >>= 1) ss += __shfl_xor(ss, o);
  if (lane == 0) red[wave] = ss;
  __syncthreads();
  float ms = (red[0] + red[1] + red[2] + red[3]) * (1.f / 4096.f);
  float sc = rsqrtf(ms + 1e-4f);
  float ga[8], gb8[8];
  *(float4*)&ga[0]  = *(const float4*)&gw[tid * 8];
  *(float4*)&ga[4]  = *(const float4*)&gw[tid * 8 + 4];
  *(float4*)&gb8[0] = *(const float4*)&gw[(256 + tid) * 8];
  *(float4*)&gb8[4] = *(const float4*)&gw[(256 + tid) * 8 + 4];
  u16x8 oa, ob;
#pragma unroll
  for (int e = 0; e < 8; ++e) {
    oa[e] = f2bf(siluf_(fa[e] * sc * ga[e]));
    ob[e] = f2bf(siluf_(fb[e] * sc * gb8[e]));
  }
  u16x8* hv = (u16x8*)(h + (long long)row * 4096);
  hv[tid] = oa;
  hv[256 + tid] = ob;
}

// ---------------------------------------------------------------------------
extern "C" void kernel_launch(void* const* d_in, const int* in_sizes, int n_in,
                              void* d_out, int out_size, void* d_ws, size_t ws_size,
                              hipStream_t stream) {
  const float* stoch  = (const float*)d_in[0];
  const float* deter  = (const float*)d_in[1];
  const float* action = (const float*)d_in[2];
  const float* demb   = (const float*)d_in[3];
  const float* W0 = (const float*)d_in[4];
  const float* b0 = (const float*)d_in[5];
  const float* g0 = (const float*)d_in[6];
  const float* W1 = (const float*)d_in[7];
  const float* b1 = (const float*)d_in[8];
  const float* g1 = (const float*)d_in[9];
  const float* W2 = (const float*)d_in[10];
  const float* b2 = (const float*)d_in[11];
  const float* g2 = (const float*)d_in[12];
  const float* W3 = (const float*)d_in[13];
  const float* b3 = (const float*)d_in[14];
  const float* g3 = (const float*)d_in[15];
  const float* Wh0 = (const float*)d_in[16];
  const float* bh0 = (const float*)d_in[17];
  const float* gh0 = (const float*)d_in[18];
  const float* Wh1 = (const float*)d_in[19];
  const float* bh1 = (const float*)d_in[20];
  const float* gh1 = (const float*)d_in[21];
  const float* Wg  = (const float*)d_in[22];
  const float* bg  = (const float*)d_in[23];
  float* out = (float*)d_out;

  char* ws = (char*)d_ws;
  unsigned short* deterB = (unsigned short*)(ws + 0);          // 33.55 MB
  unsigned short* Wgt    = (unsigned short*)(ws + 0);          // 12.58 MB (late, after deterB dead)
  unsigned short* stochB = (unsigned short*)(ws + 33554432);   //  8.39 MB
  unsigned short* W0t    = (unsigned short*)(ws + 41943040);   //  4.19 MB
  unsigned short* W1t    = (unsigned short*)(ws + 46137344);   //  1.05 MB
  unsigned short* xB     = (unsigned short*)(ws + 47185920);   // 16.78 MB
  float*          yP0    = (float*)(ws + 63963136);            // 33.55 MB (early)
  unsigned short* yB     = (unsigned short*)(ws + 63963136);   // 33.55 MB (late)
  float*          yP1    = (float*)(ws + 97517568);            //  8.39 MB
  unsigned short* Wh0t   = (unsigned short*)(ws + 105906176);  // 20.97 MB
  unsigned short* Wh1t   = (unsigned short*)(ws + 126877696);  //  4.19 MB
  unsigned short* hB     = (unsigned short*)(ws + 134217728);  // 33.55 MB
  (void)in_sizes; (void)n_in; (void)out_size; (void)ws_size;

  dim3 b256(256);
  dim3 b512(512);
  dim3 tb(32, 8);
  cvt2_bf16_k<<<dim3(20480), b256, 0, stream>>>(deter, deterB, 4194304,
                                                stoch, stochB, 1048576);
  transpose_cvt<<<dim3(16, 128, 1), tb, 0, stream>>>(W0,  W0t,  4096, 512);
  transpose_cvt<<<dim3(16, 32, 1),  tb, 0, stream>>>(W1,  W1t,  1024, 512);
  // branches 0+1: split-K x4 for branch0 (K=4096 -> 4 x 1024) + branch1
  {
    BPack p;
    for (int z = 0; z < 4; ++z)
      p.c[z] = { deterB + z * 1024, 4096, W0t + z * 1024, 4096, yP0 + (long long)z * 2097152 };
    p.c[4] = { stochB, 1024, W1t, 1024, yP1 };
    gemm8_branch<<<dim3(2, 16, 5), b512, 0, stream>>>(p);
  }
  branch23_k<<<dim3(4096, 2), b256, 0, stream>>>(action, demb, W2, b2, g2, W3, b3, g3, xB);
  epi_branch_k<<<dim3(4096, 2), b256, 0, stream>>>(yP0, yP1, b0, g0, b1, g1, xB);
  // hidden block layer 0: [deter_blk | x] @ Wh0   (N=512 -> grid.x = 2)
  transpose_cvt<<<dim3(16, 80, 8),  tb, 0, stream>>>(Wh0, Wh0t, 2560, 512);
  transpose_cvt<<<dim3(16, 16, 8),  tb, 0, stream>>>(Wh1, Wh1t, 512,  512);
  gemm8<<<dim3(2, 16, 8), b512, 0, stream>>>(deterB, 4096, 512, 512, xB, 2048, 2048,
                                             Wh0t, 2560, 512LL * 2560, yB, 4096, 512);
  // Wg transpose (gate-interleaved) after hidden0; reuses deterB space
  transpose_wg<<<dim3(48, 16, 8), tb, 0, stream>>>(Wg, Wgt);
  epi_full_k<<<dim3(4096), b256, 0, stream>>>(yB, bh0, gh0, hB);
  // hidden block layer 1   (N=512 -> grid.x = 2)
  gemm8<<<dim3(2, 16, 8), b512, 0, stream>>>(hB, 4096, 512, 512, nullptr, 0, 0,
                                             Wh1t, 512, 512LL * 512, yB, 4096, 512);
  epi_full_k<<<dim3(4096), b256, 0, stream>>>(yB, bh1, gh1, hB);
  // fused gates GEMM + GRU combine -> out (fp32), no gates round-trip
  gemm_gru<<<dim3(8, 16, 8), b512, 0, stream>>>(hB, Wgt, bg, deter, out);
}

// Round 6
// 336.016 us; speedup vs baseline: 1.8084x; 1.0498x over previous
//
#include <hip/hip_runtime.h>
#include <hip/hip_bf16.h>
#include <cstdint>

typedef __bf16 bf16x8 __attribute__((ext_vector_type(8)));
typedef float f32x4 __attribute__((ext_vector_type(4)));
typedef unsigned short u16x8 __attribute__((ext_vector_type(8)));
typedef unsigned short u16x4 __attribute__((ext_vector_type(4)));

__device__ __forceinline__ unsigned short f2bf(float f) {
  unsigned int u = __float_as_uint(f);
  u += 0x7FFFu + ((u >> 16) & 1u);
  return (unsigned short)(u >> 16);
}
__device__ __forceinline__ float bf2f(unsigned short h) {
  return __uint_as_float(((unsigned int)h) << 16);
}
__device__ __forceinline__ float frcp_(float x) { return __builtin_amdgcn_rcpf(x); }
__device__ __forceinline__ float sigmoid_fast(float x) { return frcp_(1.f + __expf(-x)); }
__device__ __forceinline__ float tanh_fast(float x) { return 1.f - 2.f * frcp_(__expf(2.f * x) + 1.f); }
__device__ __forceinline__ float siluf_(float x) { return x * sigmoid_fast(x); }

#define GLOAD_LDS16(gsrc, ldst) \
  __builtin_amdgcn_global_load_lds((const __attribute__((address_space(1))) void*)(gsrc), \
                                   (__attribute__((address_space(3))) void*)(ldst), 16, 0, 0)

#define S_BARRIER() asm volatile("s_barrier" ::: "memory")
#define WAIT_LGKM0() do { asm volatile("s_waitcnt lgkmcnt(0)" ::: "memory"); \
                          __builtin_amdgcn_sched_barrier(0); } while (0)

// XCD-aware bijective tile remap (T1). Requires nwg % 8 == 0 (all our grids).
// hw block lin (dispatch round-robins lin%8 across XCDs) -> logical tile t so
// each XCD owns a CONTIGUOUS tile chunk (x fastest => shared A/B panels stay
// in that XCD's L2).
__device__ __forceinline__ void xcd_tile(int& x, int& y, int& z) {
  const int gx = gridDim.x, gy = gridDim.y;
  const int nwg = gx * gy * gridDim.z;
  const int lin = (blockIdx.z * gy + blockIdx.y) * gx + blockIdx.x;
  const int cpx = nwg >> 3;
  const int t = (lin & 7) * cpx + (lin >> 3);
  x = t % gx;
  const int r = t / gx;
  y = r % gy;
  z = r / gy;
}

// ---------------------------------------------------------------------------
// Phased GEMM core. 256x256 tile, BK=32, 8 waves (2M x 4N), 512 threads.
// 3 LDS buffers, 2-tile lookahead, counted vmcnt(4). XOR-swizzle
// o^=((o>>7)&3)<<4 on BOTH gload source coords and ds_read addrs.
// ---------------------------------------------------------------------------
template<int F32>
__device__ __forceinline__ void gemm8_core(
    const unsigned short* __restrict__ A1, int lda1, int K1,
    const unsigned short* __restrict__ A2, int lda2, int K2,
    const unsigned short* __restrict__ Bt, int ldb,
    void* __restrict__ C, int ldc,
    int tm, int tn, unsigned short* lds)
{
  const int tid = threadIdx.x;
  const int lane = tid & 63;
  const int wave = tid >> 6;                 // 0..7
  const int wm = (wave >> 2) * 128;          // 0 / 128
  const int wn = (wave & 3) * 64;            // 0..192
  const int frow = lane & 15;
  const int chunk16 = (lane >> 4) * 16;      // byte offset of k-chunk
  const int nt = (K1 + K2) >> 5;

  auto stageA = [&](unsigned short* dstA, int ktBase) {
    const unsigned short* Ab; int alda, kloc;
    if (ktBase >= K1) { Ab = A2; alda = lda2; kloc = ktBase - K1; }
    else              { Ab = A1; alda = lda1; kloc = ktBase; }
#pragma unroll
    for (int j = 0; j < 2; ++j) {
      int o = j * 8192 + tid * 16;
      int so = o ^ (((o >> 7) & 3) << 4);
      int row = so >> 6, cb = so & 63;
      GLOAD_LDS16(Ab + (long long)(tm + row) * alda + kloc + (cb >> 1),
                  (char*)dstA + j * 8192 + wave * 1024);
    }
  };
  auto stageB = [&](unsigned short* dstB, int ktBase) {
#pragma unroll
    for (int j = 0; j < 2; ++j) {
      int o = j * 8192 + tid * 16;
      int so = o ^ (((o >> 7) & 3) << 4);
      int row = so >> 6, cb = so & 63;
      GLOAD_LDS16(Bt + (long long)(tn + row) * ldb + ktBase + (cb >> 1),
                  (char*)dstB + j * 8192 + wave * 1024);
    }
  };
  auto ldswz = [&](const unsigned short* rg, int row) -> bf16x8 {
    int o = row * 64 + chunk16;
    o ^= ((o >> 7) & 3) << 4;
    return *(const bf16x8*)((const char*)rg + o);
  };

  f32x4 acc[8][4] = {};

  unsigned short* pc = lds;
  unsigned short* pn = lds + 16384;
  unsigned short* pf = lds + 32768;

  stageA(pc, 0); stageB(pc + 8192, 0);
  stageA(pn, 32); stageB(pn + 8192, 32);
  asm volatile("s_waitcnt vmcnt(4)" ::: "memory");
  S_BARRIER();

  for (int T = 0; T < nt; ++T) {
    const unsigned short* A_ = pc;
    const unsigned short* B_ = pc + 8192;
    bf16x8 av[4], bv[4];
#pragma unroll
    for (int j = 0; j < 4; ++j) bv[j] = ldswz(B_, wn + j * 16 + frow);
#pragma unroll
    for (int i = 0; i < 4; ++i) av[i] = ldswz(A_, wm + i * 16 + frow);
    if (T + 2 < nt) stageA(pf, (T + 2) * 32);
    S_BARRIER();
    WAIT_LGKM0();
    __builtin_amdgcn_s_setprio(1);
#pragma unroll
    for (int i = 0; i < 4; ++i)
#pragma unroll
      for (int j = 0; j < 4; ++j)
        acc[i][j] = __builtin_amdgcn_mfma_f32_16x16x32_bf16(av[i], bv[j], acc[i][j], 0, 0, 0);
    __builtin_amdgcn_s_setprio(0);
    __builtin_amdgcn_sched_barrier(0);
    S_BARRIER();
#pragma unroll
    for (int i = 0; i < 4; ++i) av[i] = ldswz(A_, wm + 64 + i * 16 + frow);
    if (T + 2 < nt) {
      stageB(pf + 8192, (T + 2) * 32);
      asm volatile("s_waitcnt vmcnt(4)" ::: "memory");
    } else if (T + 1 < nt) {
      asm volatile("s_waitcnt vmcnt(0)" ::: "memory");
    }
    S_BARRIER();
    WAIT_LGKM0();
    __builtin_amdgcn_s_setprio(1);
#pragma unroll
    for (int i = 0; i < 4; ++i)
#pragma unroll
      for (int j = 0; j < 4; ++j)
        acc[4 + i][j] = __builtin_amdgcn_mfma_f32_16x16x32_bf16(av[i], bv[j], acc[4 + i][j], 0, 0, 0);
    __builtin_amdgcn_s_setprio(0);
    __builtin_amdgcn_sched_barrier(0);
    S_BARRIER();
    unsigned short* t = pc; pc = pn; pn = pf; pf = t;
  }

  const int cr = (lane >> 4) * 4;
  const int cc = lane & 15;
#pragma unroll
  for (int mf = 0; mf < 8; ++mf) {
    const int r0 = tm + wm + mf * 16 + cr;
#pragma unroll
    for (int j = 0; j < 4; ++j) {
      const int col = tn + wn + j * 16 + cc;
#pragma unroll
      for (int i = 0; i < 4; ++i) {
        if (F32) ((float*)C)[(long long)(r0 + i) * ldc + col] = acc[mf][j][i];
        else ((unsigned short*)C)[(long long)(r0 + i) * ldc + col] = f2bf(acc[mf][j][i]);
      }
    }
  }
}

// Batched (z = group) two-segment GEMM, bf16 output. XCD-swizzled tiles.
__global__ __launch_bounds__(512, 2) void gemm8(
    const unsigned short* __restrict__ A1, int lda1, long long a1_bs, int K1,
    const unsigned short* __restrict__ A2, int lda2, int K2,
    const unsigned short* __restrict__ Bt, int ldb, long long bt_bs,
    unsigned short* __restrict__ C, int ldc, long long c_bs)
{
  __shared__ unsigned short lds[3 * 16384];
  int tx, ty, g;
  xcd_tile(tx, ty, g);
  gemm8_core<0>(A1 + (long long)g * a1_bs, lda1, K1, A2, lda2, K2,
                Bt + (long long)g * bt_bs, ldb,
                C + (long long)g * c_bs, ldc,
                ty * 256, tx * 256, lds);
}

// Branch pack: z selects one of 5 configs (4x split-K of branch0 + branch1)
struct BCfg { const unsigned short* A; int lda; const unsigned short* Bt; int ldb; float* C; };
struct BPack { BCfg c[5]; };
__global__ __launch_bounds__(512, 2) void gemm8_branch(BPack p) {
  __shared__ unsigned short lds[3 * 16384];
  int tx, ty, z;
  xcd_tile(tx, ty, z);
  BCfg c = p.c[z];
  gemm8_core<1>(c.A, c.lda, 1024, nullptr, 0, 0, c.Bt, c.ldb, c.C, 512,
                ty * 256, tx * 256, lds);
}

// ---------------------------------------------------------------------------
// Fused gates GEMM + GRU combine. Tile 256M x 192N(nn), BK=32, 8 waves
// (2 M-halves x 4 N-stripes of 48). Wgt columns pre-permuted so
// nn = (o>>4)*48 + gate*16 + (o&15). XCD swizzle maps one group per XCD
// (A-panel 4MB + B-panel 1.6MB resident in that XCD's L2).
// deter read as bf16 (deterB) to halve the blend-input fetch.
// ---------------------------------------------------------------------------
__global__ __launch_bounds__(512, 2) void gemm_gru(
    const unsigned short* __restrict__ hB,    // [4096][4096] bf16
    const unsigned short* __restrict__ Wgt,   // [8][1536 nn][512] bf16
    const float* __restrict__ bg,
    const unsigned short* __restrict__ deterB,// [4096][4096] bf16
    float* __restrict__ out)
{
  __shared__ unsigned short lds[3 * 14336];   // per buf: A 16KB + B 12KB
  int txi, tyi, g;
  xcd_tile(txi, tyi, g);
  const int tm = tyi * 256;
  const int tn = txi * 192;
  const unsigned short* A  = hB + g * 512;
  const unsigned short* Bt = Wgt + (long long)g * 1536 * 512;
  const int tid = threadIdx.x, lane = tid & 63, wave = tid >> 6;
  const int wm = (wave >> 2) * 128;
  const int wv = wave & 3;
  const int frow = lane & 15, chunk16 = (lane >> 4) * 16;
  const bool wlow = (wave < 4);
  const int nt = 16;                          // K=512 / 32

  auto stageA = [&](unsigned short* buf, int kt) {
#pragma unroll
    for (int j = 0; j < 2; ++j) {
      int o = j * 8192 + tid * 16;
      int so = o ^ (((o >> 7) & 3) << 4);
      int row = so >> 6, cb = so & 63;
      GLOAD_LDS16(A + (long long)(tm + row) * 4096 + kt + (cb >> 1),
                  (char*)buf + j * 8192 + wave * 1024);
    }
  };
  auto stageB = [&](unsigned short* buf, int kt) {
    char* bb = (char*)(buf + 8192);
    {
      int o = tid * 16;
      int so = o ^ (((o >> 7) & 3) << 4);
      int row = so >> 6, cb = so & 63;
      GLOAD_LDS16(Bt + (long long)(tn + row) * 512 + kt + (cb >> 1),
                  bb + wave * 1024);
    }
    if (tid < 256) {                          // waves 0-3 only (uniform per wave)
      int o = 8192 + tid * 16;
      int so = o ^ (((o >> 7) & 3) << 4);
      int row = so >> 6, cb = so & 63;
      GLOAD_LDS16(Bt + (long long)(tn + row) * 512 + kt + (cb >> 1),
                  bb + 8192 + wave * 1024);
    }
  };
  auto ldA = [&](const unsigned short* buf, int row) -> bf16x8 {
    int o = row * 64 + chunk16; o ^= ((o >> 7) & 3) << 4;
    return *(const bf16x8*)((const char*)buf + o);
  };
  auto ldB = [&](const unsigned short* buf, int nf) -> bf16x8 {
    int row = wv * 48 + nf * 16 + frow;
    int o = row * 64 + chunk16; o ^= ((o >> 7) & 3) << 4;
    return *(const bf16x8*)((const char*)(buf + 8192) + o);
  };
  auto wait_pref = [&]() {
    if (wlow) asm volatile("s_waitcnt vmcnt(4)" ::: "memory");
    else      asm volatile("s_waitcnt vmcnt(3)" ::: "memory");
  };

  f32x4 acc[8][3] = {};

  unsigned short* pc = lds;
  unsigned short* pn = lds + 14336;
  unsigned short* pf = lds + 28672;

  stageA(pc, 0); stageB(pc, 0);
  stageA(pn, 32); stageB(pn, 32);
  wait_pref();
  S_BARRIER();

  for (int T = 0; T < nt; ++T) {
    bf16x8 av[4], bv[3];
#pragma unroll
    for (int j = 0; j < 3; ++j) bv[j] = ldB(pc, j);
#pragma unroll
    for (int i = 0; i < 4; ++i) av[i] = ldA(pc, wm + i * 16 + frow);
    if (T + 2 < nt) stageA(pf, (T + 2) * 32);
    S_BARRIER();
    WAIT_LGKM0();
    __builtin_amdgcn_s_setprio(1);
#pragma unroll
    for (int i = 0; i < 4; ++i)
#pragma unroll
      for (int j = 0; j < 3; ++j)
        acc[i][j] = __builtin_amdgcn_mfma_f32_16x16x32_bf16(av[i], bv[j], acc[i][j], 0, 0, 0);
    __builtin_amdgcn_s_setprio(0);
    __builtin_amdgcn_sched_barrier(0);
    S_BARRIER();
#pragma unroll
    for (int i = 0; i < 4; ++i) av[i] = ldA(pc, wm + 64 + i * 16 + frow);
    if (T + 2 < nt) {
      stageB(pf, (T + 2) * 32);
      wait_pref();
    } else if (T + 1 < nt) {
      asm volatile("s_waitcnt vmcnt(0)" ::: "memory");
    }
    S_BARRIER();
    WAIT_LGKM0();
    __builtin_amdgcn_s_setprio(1);
#pragma unroll
    for (int i = 0; i < 4; ++i)
#pragma unroll
      for (int j = 0; j < 3; ++j)
        acc[4 + i][j] = __builtin_amdgcn_mfma_f32_16x16x32_bf16(av[i], bv[j], acc[4 + i][j], 0, 0, 0);
    __builtin_amdgcn_s_setprio(0);
    __builtin_amdgcn_sched_barrier(0);
    S_BARRIER();
    unsigned short* t = pc; pc = pn; pn = pf; pf = t;
  }

  // GRU combine epilogue: lane holds reset/cand/update for (r, o_col)
  const int cr = (lane >> 4) * 4, cc = lane & 15;
  const int o_col = (txi * 4 + wv) * 16 + cc;
  const int gcol = g * 512 + o_col;
  const float bgr = bg[g * 1536 + o_col];
  const float bgc = bg[g * 1536 + 512 + o_col];
  const float bgu = bg[g * 1536 + 1024 + o_col];
#pragma unroll
  for (int mf = 0; mf < 8; ++mf) {
    const int r0 = tm + wm + mf * 16 + cr;
#pragma unroll
    for (int i = 0; i < 4; ++i) {
      const long long off = (long long)(r0 + i) * 4096 + gcol;
      float dt = bf2f(deterB[off]);
      float reset = sigmoid_fast(acc[mf][0][i] + bgr);
      float cand  = tanh_fast(reset * (acc[mf][1][i] + bgc));
      float upd   = sigmoid_fast(acc[mf][2][i] + bgu - 1.f);
      out[off] = upd * cand + (1.f - upd) * dt;
    }
  }
}

// ---------------------------------------------------------------------------
// fp32 -> bf16 cast for two buffers in one launch (4 elems / thread)
// ---------------------------------------------------------------------------
__global__ void cvt2_bf16_k(const float* __restrict__ sa, unsigned short* __restrict__ da, int n4a,
                            const float* __restrict__ sb, unsigned short* __restrict__ db, int n4b) {
  int i = blockIdx.x * 256 + threadIdx.x;
  const float* s; unsigned short* d;
  if (i < n4a) { s = sa; d = da; }
  else { i -= n4a; if (i >= n4b) return; s = sb; d = db; }
  float4 v = ((const float4*)s)[i];
  u16x4 o;
  o.x = f2bf(v.x); o.y = f2bf(v.y); o.z = f2bf(v.z); o.w = f2bf(v.w);
  ((u16x4*)d)[i] = o;
}

// ---------------------------------------------------------------------------
// Batched transpose + cast: src fp32 [z][R][C] -> dst bf16 [z][C][R]
// ---------------------------------------------------------------------------
__global__ void transpose_cvt(const float* __restrict__ src, unsigned short* __restrict__ dst,
                              int R, int C) {
  __shared__ float t[32][33];
  const long long bOff = (long long)blockIdx.z * R * C;
  src += bOff; dst += bOff;
  const int c0 = blockIdx.x * 32, r0 = blockIdx.y * 32;
  const int tx = threadIdx.x, ty = threadIdx.y;  // (32,8)
#pragma unroll
  for (int i = 0; i < 4; ++i) {
    int r = r0 + ty + i * 8, c = c0 + tx;
    if (r < R && c < C) t[ty + i * 8][tx] = src[(long long)r * C + c];
  }
  __syncthreads();
#pragma unroll
  for (int i = 0; i < 4; ++i) {
    int c = c0 + ty + i * 8, r = r0 + tx;
    if (r < R && c < C) dst[(long long)c * R + r] = f2bf(t[tx][ty + i * 8]);
  }
}

// ---------------------------------------------------------------------------
// Wg transpose with gate-interleaved row permutation:
// src [8][512][1536] f32, dst [8][1536][512] bf16, row nn = (o>>4)*48+gate*16+(o&15)
// ---------------------------------------------------------------------------
__global__ void transpose_wg(const float* __restrict__ src, unsigned short* __restrict__ dst) {
  __shared__ float t[32][33];
  const int gz = blockIdx.z;
  src += (long long)gz * 512 * 1536;
  dst += (long long)gz * 1536 * 512;
  const int c0 = blockIdx.x * 32, r0 = blockIdx.y * 32;
  const int tx = threadIdx.x, ty = threadIdx.y;  // (32,8)
#pragma unroll
  for (int i = 0; i < 4; ++i)
    t[ty + i * 8][tx] = src[(long long)(r0 + ty + i * 8) * 1536 + c0 + tx];
  __syncthreads();
#pragma unroll
  for (int i = 0; i < 4; ++i) {
    int c = c0 + ty + i * 8;
    int gate = c >> 9, o = c & 511;
    int nn = (o >> 4) * 48 + gate * 16 + (o & 15);
    dst[(long long)nn * 512 + r0 + tx] = f2bf(t[tx][ty + i * 8]);
  }
}

// ---------------------------------------------------------------------------
// Merged branch epilogues. blockIdx.y: 0/1 -> branch0/1 (sum split-K f32
// partials + bias -> RMSNorm(512) -> SiLU -> x cols), 2/3 -> branch2/3
// (tiny-K fp32 GEMM + RMSNorm + SiLU).
// ---------------------------------------------------------------------------
__global__ __launch_bounds__(256) void branch_epi_k(
    const float* __restrict__ yP0, const float* __restrict__ yP1,
    const float* __restrict__ b0, const float* __restrict__ g0,
    const float* __restrict__ b1, const float* __restrict__ g1,
    const float* __restrict__ action, const float* __restrict__ demb,
    const float* __restrict__ W2, const float* __restrict__ b2, const float* __restrict__ g2,
    const float* __restrict__ W3, const float* __restrict__ b3, const float* __restrict__ g3,
    unsigned short* __restrict__ x)
{
  const int row = blockIdx.x, br = blockIdx.y;
  const int tid = threadIdx.x, lane = tid & 63, wave = tid >> 6;
  __shared__ float red[4];
  __shared__ float a[32];
  float v0, v1;
  const float* gg;
  if (br == 0) {
    const float* p = yP0 + (long long)row * 512;
    v0 = b0[tid]; v1 = b0[tid + 256];
#pragma unroll
    for (int c = 0; c < 4; ++c) {
      v0 += p[c * 2097152 + tid];
      v1 += p[c * 2097152 + tid + 256];
    }
    gg = g0;
  } else if (br == 1) {
    const float* p = yP1 + (long long)row * 512;
    v0 = b1[tid] + p[tid];
    v1 = b1[tid + 256] + p[tid + 256];
    gg = g1;
  } else {
    const int K = (br == 3) ? 16 : 32;
    const float* W  = (br == 3) ? W3 : W2;
    const float* bb = (br == 3) ? b3 : b2;
    gg = (br == 3) ? g3 : g2;
    if (tid < K) {
      float t = (br == 3) ? demb[(long long)row * 16 + tid]
                          : action[(long long)row * 32 + tid];
      if (br == 2) t = t / fmaxf(fabsf(t), 1.f);
      a[tid] = t;
    }
    __syncthreads();
    v0 = bb[tid]; v1 = bb[tid + 256];
    for (int k = 0; k < K; ++k) {
      float av = a[k];
      v0 += av * W[k * 512 + tid];
      v1 += av * W[k * 512 + tid + 256];
    }
  }
  float ss = v0 * v0 + v1 * v1;
  for (int o = 32; o > 0; o >>= 1) ss += __shfl_xor(ss, o);
  if (lane == 0) red[wave] = ss;
  __syncthreads();
  float ms = (red[0] + red[1] + red[2] + red[3]) * (1.f / 512.f);
  float sc = rsqrtf(ms + 1e-4f);
  unsigned short* xr = x + (long long)row * 2048 + br * 512;
  xr[tid]       = f2bf(siluf_(v0 * sc * gg[tid]));
  xr[tid + 256] = f2bf(siluf_(v1 * sc * gg[tid + 256]));
}

// ---------------------------------------------------------------------------
// Full-width (4096) epilogue: y(bf16) + bias -> RMSNorm -> SiLU -> h(bf16).
// Register-resident (no LDS round-trip).
// ---------------------------------------------------------------------------
__global__ __launch_bounds__(256) void epi_full_k(
    const unsigned short* __restrict__ y, const float* __restrict__ bias,
    const float* __restrict__ gw, unsigned short* __restrict__ h)
{
  const int row = blockIdx.x;
  __shared__ float red[4];
  const int tid = threadIdx.x, lane = tid & 63, wave = tid >> 6;
  const u16x8* yv = (const u16x8*)(y + (long long)row * 4096);
  u16x8 ta = yv[tid], tb = yv[256 + tid];
  float ba[8], bb8[8];
  *(float4*)&ba[0]  = *(const float4*)&bias[tid * 8];
  *(float4*)&ba[4]  = *(const float4*)&bias[tid * 8 + 4];
  *(float4*)&bb8[0] = *(const float4*)&bias[(256 + tid) * 8];
  *(float4*)&bb8[4] = *(const float4*)&bias[(256 + tid) * 8 + 4];
  float fa[8], fb[8];
  float ss = 0.f;
#pragma unroll
  for (int e = 0; e < 8; ++e) {
    fa[e] = bf2f(ta[e]) + ba[e];  ss += fa[e] * fa[e];
    fb[e] = bf2f(tb[e]) + bb8[e]; ss += fb[e] * fb[e];
  }
  for (int o = 32; o > 0; o >>= 1) ss += __shfl_xor(ss, o);
  if (lane == 0) red[wave] = ss;
  __syncthreads();
  float ms = (red[0] + red[1] + red[2] + red[3]) * (1.f / 4096.f);
  float sc = rsqrtf(ms + 1e-4f);
  float ga[8], gb8[8];
  *(float4*)&ga[0]  = *(const float4*)&gw[tid * 8];
  *(float4*)&ga[4]  = *(const float4*)&gw[tid * 8 + 4];
  *(float4*)&gb8[0] = *(const float4*)&gw[(256 + tid) * 8];
  *(float4*)&gb8[4] = *(const float4*)&gw[(256 + tid) * 8 + 4];
  u16x8 oa, ob;
#pragma unroll
  for (int e = 0; e < 8; ++e) {
    oa[e] = f2bf(siluf_(fa[e] * sc * ga[e]));
    ob[e] = f2bf(siluf_(fb[e] * sc * gb8[e]));
  }
  u16x8* hv = (u16x8*)(h + (long long)row * 4096);
  hv[tid] = oa;
  hv[256 + tid] = ob;
}

// ---------------------------------------------------------------------------
extern "C" void kernel_launch(void* const* d_in, const int* in_sizes, int n_in,
                              void* d_out, int out_size, void* d_ws, size_t ws_size,
                              hipStream_t stream) {
  const float* stoch  = (const float*)d_in[0];
  const float* deter  = (const float*)d_in[1];
  const float* action = (const float*)d_in[2];
  const float* demb   = (const float*)d_in[3];
  const float* W0 = (const float*)d_in[4];
  const float* b0 = (const float*)d_in[5];
  const float* g0 = (const float*)d_in[6];
  const float* W1 = (const float*)d_in[7];
  const float* b1 = (const float*)d_in[8];
  const float* g1 = (const float*)d_in[9];
  const float* W2 = (const float*)d_in[10];
  const float* b2 = (const float*)d_in[11];
  const float* g2 = (const float*)d_in[12];
  const float* W3 = (const float*)d_in[13];
  const float* b3 = (const float*)d_in[14];
  const float* g3 = (const float*)d_in[15];
  const float* Wh0 = (const float*)d_in[16];
  const float* bh0 = (const float*)d_in[17];
  const float* gh0 = (const float*)d_in[18];
  const float* Wh1 = (const float*)d_in[19];
  const float* bh1 = (const float*)d_in[20];
  const float* gh1 = (const float*)d_in[21];
  const float* Wg  = (const float*)d_in[22];
  const float* bg  = (const float*)d_in[23];
  float* out = (float*)d_out;

  // layout (bytes). deterB now lives to the END (gemm_gru blend input).
  // Wgt overlays the dead Wh0t region (transpose_wg launches after hidden0).
  char* ws = (char*)d_ws;
  unsigned short* deterB = (unsigned short*)(ws + 0);          // 33.55 MB, whole run
  unsigned short* stochB = (unsigned short*)(ws + 33554432);   //  8.39 MB
  unsigned short* W0t    = (unsigned short*)(ws + 41943040);   //  4.19 MB
  unsigned short* W1t    = (unsigned short*)(ws + 46137344);   //  1.05 MB
  unsigned short* xB     = (unsigned short*)(ws + 47185920);   // 16.78 MB
  float*          yP0    = (float*)(ws + 63963136);            // 33.55 MB (early)
  unsigned short* yB     = (unsigned short*)(ws + 63963136);   // 33.55 MB (late)
  float*          yP1    = (float*)(ws + 97517568);            //  8.39 MB
  unsigned short* Wh0t   = (unsigned short*)(ws + 105906176);  // 20.97 MB (dead after hidden0)
  unsigned short* Wgt    = (unsigned short*)(ws + 105906176);  // 12.58 MB (late, overlays Wh0t)
  unsigned short* Wh1t   = (unsigned short*)(ws + 126877696);  //  4.19 MB
  unsigned short* hB     = (unsigned short*)(ws + 134217728);  // 33.55 MB -> 167.8 MB total
  (void)in_sizes; (void)n_in; (void)out_size; (void)ws_size;

  dim3 b256(256);
  dim3 b512(512);
  dim3 tb(32, 8);
  cvt2_bf16_k<<<dim3(20480), b256, 0, stream>>>(deter, deterB, 4194304,
                                                stoch, stochB, 1048576);
  transpose_cvt<<<dim3(16, 128, 1), tb, 0, stream>>>(W0,  W0t,  4096, 512);
  transpose_cvt<<<dim3(16, 32, 1),  tb, 0, stream>>>(W1,  W1t,  1024, 512);
  // branches 0+1: split-K x4 for branch0 (K=4096 -> 4 x 1024) + branch1
  {
    BPack p;
    for (int z = 0; z < 4; ++z)
      p.c[z] = { deterB + z * 1024, 4096, W0t + z * 1024, 4096, yP0 + (long long)z * 2097152 };
    p.c[4] = { stochB, 1024, W1t, 1024, yP1 };
    gemm8_branch<<<dim3(2, 16, 5), b512, 0, stream>>>(p);
  }
  // all four branch epilogues in one launch
  branch_epi_k<<<dim3(4096, 4), b256, 0, stream>>>(yP0, yP1, b0, g0, b1, g1,
                                                   action, demb, W2, b2, g2, W3, b3, g3, xB);
  // hidden block layer 0: [deter_blk | x] @ Wh0   (N=512 -> grid.x = 2)
  transpose_cvt<<<dim3(16, 80, 8),  tb, 0, stream>>>(Wh0, Wh0t, 2560, 512);
  transpose_cvt<<<dim3(16, 16, 8),  tb, 0, stream>>>(Wh1, Wh1t, 512,  512);
  gemm8<<<dim3(2, 16, 8), b512, 0, stream>>>(deterB, 4096, 512, 512, xB, 2048, 2048,
                                             Wh0t, 2560, 512LL * 2560, yB, 4096, 512);
  // Wg transpose (gate-interleaved) after hidden0; overlays dead Wh0t
  transpose_wg<<<dim3(48, 16, 8), tb, 0, stream>>>(Wg, Wgt);
  epi_full_k<<<dim3(4096), b256, 0, stream>>>(yB, bh0, gh0, hB);
  // hidden block layer 1   (N=512 -> grid.x = 2)
  gemm8<<<dim3(2, 16, 8), b512, 0, stream>>>(hB, 4096, 512, 512, nullptr, 0, 0,
                                             Wh1t, 512, 512LL * 512, yB, 4096, 512);
  epi_full_k<<<dim3(4096), b256, 0, stream>>>(yB, bh1, gh1, hB);
  // fused gates GEMM + GRU combine -> out (fp32); one group per XCD
  gemm_gru<<<dim3(8, 16, 8), b512, 0, stream>>>(hB, Wgt, bg, deterB, out);
}

// Round 7
// 329.282 us; speedup vs baseline: 1.8454x; 1.0204x over previous
//
#include <hip/hip_runtime.h>
#include <hip/hip_bf16.h>
#include <cstdint>

typedef __bf16 bf16x8 __attribute__((ext_vector_type(8)));
typedef float f32x4 __attribute__((ext_vector_type(4)));
typedef unsigned short u16x8 __attribute__((ext_vector_type(8)));
typedef unsigned short u16x4 __attribute__((ext_vector_type(4)));

__device__ __forceinline__ unsigned short f2bf(float f) {
  unsigned int u = __float_as_uint(f);
  u += 0x7FFFu + ((u >> 16) & 1u);
  return (unsigned short)(u >> 16);
}
__device__ __forceinline__ float bf2f(unsigned short h) {
  return __uint_as_float(((unsigned int)h) << 16);
}
__device__ __forceinline__ float frcp_(float x) { return __builtin_amdgcn_rcpf(x); }
__device__ __forceinline__ float sigmoid_fast(float x) { return frcp_(1.f + __expf(-x)); }
__device__ __forceinline__ float tanh_fast(float x) { return 1.f - 2.f * frcp_(__expf(2.f * x) + 1.f); }
__device__ __forceinline__ float siluf_(float x) { return x * sigmoid_fast(x); }

#define GLOAD_LDS16(gsrc, ldst) \
  __builtin_amdgcn_global_load_lds((const __attribute__((address_space(1))) void*)(gsrc), \
                                   (__attribute__((address_space(3))) void*)(ldst), 16, 0, 0)

#define S_BARRIER() asm volatile("s_barrier" ::: "memory")
#define WAIT_LGKM0() do { asm volatile("s_waitcnt lgkmcnt(0)" ::: "memory"); \
                          __builtin_amdgcn_sched_barrier(0); } while (0)

// XCD-aware bijective tile remap (T1). Requires nwg % 8 == 0 (all our grids).
__device__ __forceinline__ void xcd_tile(int& x, int& y, int& z) {
  const int gx = gridDim.x, gy = gridDim.y;
  const int nwg = gx * gy * gridDim.z;
  const int lin = (blockIdx.z * gy + blockIdx.y) * gx + blockIdx.x;
  const int cpx = nwg >> 3;
  const int t = (lin & 7) * cpx + (lin >> 3);
  x = t % gx;
  const int r = t / gx;
  y = r % gy;
  z = r / gy;
}

// ---------------------------------------------------------------------------
// Phased GEMM core v2: 256x256 tile, BK=32, 8 waves (2M x 4N), 512 threads.
// 3 LDS buffers, 2-tile lookahead, counted vmcnt(4), and ONE barrier per
// K-tile (no mid-tile barriers): per tile {ds_read bv+av ; stage T+2 ;
// lgkmcnt(0) ; 16 MFMA ; ds_read av' ; lgkmcnt(0) ; 16 MFMA ; vmcnt(4) ;
// s_barrier}. Waves de-synchronize within the tile so one wave's LDS reads
// overlap another's MFMA (m114 mechanism, intra-block).
// Rotation safety: pf at tile T was pc at T-1 (reads done at T-1's barrier);
// end-of-T vmcnt(4) retires exactly T+1's 4 loads (8 outstanding).
// ---------------------------------------------------------------------------
template<int F32>
__device__ __forceinline__ void gemm8_core(
    const unsigned short* __restrict__ A1, int lda1, int K1,
    const unsigned short* __restrict__ A2, int lda2, int K2,
    const unsigned short* __restrict__ Bt, int ldb,
    void* __restrict__ C, int ldc,
    int tm, int tn, unsigned short* lds)
{
  const int tid = threadIdx.x;
  const int lane = tid & 63;
  const int wave = tid >> 6;                 // 0..7
  const int wm = (wave >> 2) * 128;          // 0 / 128
  const int wn = (wave & 3) * 64;            // 0..192
  const int frow = lane & 15;
  const int chunk16 = (lane >> 4) * 16;      // byte offset of k-chunk
  const int nt = (K1 + K2) >> 5;

  auto stageA = [&](unsigned short* dstA, int ktBase) {
    const unsigned short* Ab; int alda, kloc;
    if (ktBase >= K1) { Ab = A2; alda = lda2; kloc = ktBase - K1; }
    else              { Ab = A1; alda = lda1; kloc = ktBase; }
#pragma unroll
    for (int j = 0; j < 2; ++j) {
      int o = j * 8192 + tid * 16;
      int so = o ^ (((o >> 7) & 3) << 4);
      int row = so >> 6, cb = so & 63;
      GLOAD_LDS16(Ab + (long long)(tm + row) * alda + kloc + (cb >> 1),
                  (char*)dstA + j * 8192 + wave * 1024);
    }
  };
  auto stageB = [&](unsigned short* dstB, int ktBase) {
#pragma unroll
    for (int j = 0; j < 2; ++j) {
      int o = j * 8192 + tid * 16;
      int so = o ^ (((o >> 7) & 3) << 4);
      int row = so >> 6, cb = so & 63;
      GLOAD_LDS16(Bt + (long long)(tn + row) * ldb + ktBase + (cb >> 1),
                  (char*)dstB + j * 8192 + wave * 1024);
    }
  };
  auto ldswz = [&](const unsigned short* rg, int row) -> bf16x8 {
    int o = row * 64 + chunk16;
    o ^= ((o >> 7) & 3) << 4;
    return *(const bf16x8*)((const char*)rg + o);
  };

  f32x4 acc[8][4] = {};

  unsigned short* pc = lds;
  unsigned short* pn = lds + 16384;
  unsigned short* pf = lds + 32768;

  stageA(pc, 0); stageB(pc + 8192, 0);
  stageA(pn, 32); stageB(pn + 8192, 32);
  asm volatile("s_waitcnt vmcnt(4)" ::: "memory");
  S_BARRIER();

  for (int T = 0; T < nt; ++T) {
    bf16x8 av[4], bv[4];
#pragma unroll
    for (int j = 0; j < 4; ++j) bv[j] = ldswz(pc + 8192, wn + j * 16 + frow);
#pragma unroll
    for (int i = 0; i < 4; ++i) av[i] = ldswz(pc, wm + i * 16 + frow);
    if (T + 2 < nt) { stageA(pf, (T + 2) * 32); stageB(pf + 8192, (T + 2) * 32); }
    WAIT_LGKM0();
    __builtin_amdgcn_s_setprio(1);
#pragma unroll
    for (int i = 0; i < 4; ++i)
#pragma unroll
      for (int j = 0; j < 4; ++j)
        acc[i][j] = __builtin_amdgcn_mfma_f32_16x16x32_bf16(av[i], bv[j], acc[i][j], 0, 0, 0);
    __builtin_amdgcn_s_setprio(0);
    __builtin_amdgcn_sched_barrier(0);
#pragma unroll
    for (int i = 0; i < 4; ++i) av[i] = ldswz(pc, wm + 64 + i * 16 + frow);
    WAIT_LGKM0();
    __builtin_amdgcn_s_setprio(1);
#pragma unroll
    for (int i = 0; i < 4; ++i)
#pragma unroll
      for (int j = 0; j < 4; ++j)
        acc[4 + i][j] = __builtin_amdgcn_mfma_f32_16x16x32_bf16(av[i], bv[j], acc[4 + i][j], 0, 0, 0);
    __builtin_amdgcn_s_setprio(0);
    __builtin_amdgcn_sched_barrier(0);
    if (T + 2 < nt) asm volatile("s_waitcnt vmcnt(4)" ::: "memory");
    else            asm volatile("s_waitcnt vmcnt(0)" ::: "memory");
    S_BARRIER();
    unsigned short* t = pc; pc = pn; pn = pf; pf = t;
  }

  const int cr = (lane >> 4) * 4;
  const int cc = lane & 15;
#pragma unroll
  for (int mf = 0; mf < 8; ++mf) {
    const int r0 = tm + wm + mf * 16 + cr;
#pragma unroll
    for (int j = 0; j < 4; ++j) {
      const int col = tn + wn + j * 16 + cc;
#pragma unroll
      for (int i = 0; i < 4; ++i) {
        if (F32) ((float*)C)[(long long)(r0 + i) * ldc + col] = acc[mf][j][i];
        else ((unsigned short*)C)[(long long)(r0 + i) * ldc + col] = f2bf(acc[mf][j][i]);
      }
    }
  }
}

// Batched (z = group) two-segment GEMM, bf16 output. XCD-swizzled tiles.
__global__ __launch_bounds__(512, 2) void gemm8(
    const unsigned short* __restrict__ A1, int lda1, long long a1_bs, int K1,
    const unsigned short* __restrict__ A2, int lda2, int K2,
    const unsigned short* __restrict__ Bt, int ldb, long long bt_bs,
    unsigned short* __restrict__ C, int ldc, long long c_bs)
{
  __shared__ unsigned short lds[3 * 16384];
  int tx, ty, g;
  xcd_tile(tx, ty, g);
  gemm8_core<0>(A1 + (long long)g * a1_bs, lda1, K1, A2, lda2, K2,
                Bt + (long long)g * bt_bs, ldb,
                C + (long long)g * c_bs, ldc,
                ty * 256, tx * 256, lds);
}

// Branch pack: z selects one of 7 configs (6x split-K of branch0 + branch1)
struct BCfg { const unsigned short* A; int lda; int K;
              const unsigned short* Bt; int ldb; float* C; };
struct BPack { BCfg c[7]; };
__global__ __launch_bounds__(512, 2) void gemm8_branch(BPack p) {
  __shared__ unsigned short lds[3 * 16384];
  int tx, ty, z;
  xcd_tile(tx, ty, z);
  BCfg c = p.c[z];
  gemm8_core<1>(c.A, c.lda, c.K, nullptr, 0, 0, c.Bt, c.ldb, c.C, 512,
                ty * 256, tx * 256, lds);
}

// ---------------------------------------------------------------------------
// Fused gates GEMM + GRU combine (UNCHANGED this round: control vs gemm8's
// new 1-barrier schedule). Tile 256M x 192N(nn), BK=32, 8 waves.
// ---------------------------------------------------------------------------
__global__ __launch_bounds__(512, 2) void gemm_gru(
    const unsigned short* __restrict__ hB,
    const unsigned short* __restrict__ Wgt,
    const float* __restrict__ bg,
    const unsigned short* __restrict__ deterB,
    float* __restrict__ out)
{
  __shared__ unsigned short lds[3 * 14336];
  int txi, tyi, g;
  xcd_tile(txi, tyi, g);
  const int tm = tyi * 256;
  const int tn = txi * 192;
  const unsigned short* A  = hB + g * 512;
  const unsigned short* Bt = Wgt + (long long)g * 1536 * 512;
  const int tid = threadIdx.x, lane = tid & 63, wave = tid >> 6;
  const int wm = (wave >> 2) * 128;
  const int wv = wave & 3;
  const int frow = lane & 15, chunk16 = (lane >> 4) * 16;
  const bool wlow = (wave < 4);
  const int nt = 16;

  auto stageA = [&](unsigned short* buf, int kt) {
#pragma unroll
    for (int j = 0; j < 2; ++j) {
      int o = j * 8192 + tid * 16;
      int so = o ^ (((o >> 7) & 3) << 4);
      int row = so >> 6, cb = so & 63;
      GLOAD_LDS16(A + (long long)(tm + row) * 4096 + kt + (cb >> 1),
                  (char*)buf + j * 8192 + wave * 1024);
    }
  };
  auto stageB = [&](unsigned short* buf, int kt) {
    char* bb = (char*)(buf + 8192);
    {
      int o = tid * 16;
      int so = o ^ (((o >> 7) & 3) << 4);
      int row = so >> 6, cb = so & 63;
      GLOAD_LDS16(Bt + (long long)(tn + row) * 512 + kt + (cb >> 1),
                  bb + wave * 1024);
    }
    if (tid < 256) {
      int o = 8192 + tid * 16;
      int so = o ^ (((o >> 7) & 3) << 4);
      int row = so >> 6, cb = so & 63;
      GLOAD_LDS16(Bt + (long long)(tn + row) * 512 + kt + (cb >> 1),
                  bb + 8192 + wave * 1024);
    }
  };
  auto ldA = [&](const unsigned short* buf, int row) -> bf16x8 {
    int o = row * 64 + chunk16; o ^= ((o >> 7) & 3) << 4;
    return *(const bf16x8*)((const char*)buf + o);
  };
  auto ldB = [&](const unsigned short* buf, int nf) -> bf16x8 {
    int row = wv * 48 + nf * 16 + frow;
    int o = row * 64 + chunk16; o ^= ((o >> 7) & 3) << 4;
    return *(const bf16x8*)((const char*)(buf + 8192) + o);
  };
  auto wait_pref = [&]() {
    if (wlow) asm volatile("s_waitcnt vmcnt(4)" ::: "memory");
    else      asm volatile("s_waitcnt vmcnt(3)" ::: "memory");
  };

  f32x4 acc[8][3] = {};

  unsigned short* pc = lds;
  unsigned short* pn = lds + 14336;
  unsigned short* pf = lds + 28672;

  stageA(pc, 0); stageB(pc, 0);
  stageA(pn, 32); stageB(pn, 32);
  wait_pref();
  S_BARRIER();

  for (int T = 0; T < nt; ++T) {
    bf16x8 av[4], bv[3];
#pragma unroll
    for (int j = 0; j < 3; ++j) bv[j] = ldB(pc, j);
#pragma unroll
    for (int i = 0; i < 4; ++i) av[i] = ldA(pc, wm + i * 16 + frow);
    if (T + 2 < nt) stageA(pf, (T + 2) * 32);
    S_BARRIER();
    WAIT_LGKM0();
    __builtin_amdgcn_s_setprio(1);
#pragma unroll
    for (int i = 0; i < 4; ++i)
#pragma unroll
      for (int j = 0; j < 3; ++j)
        acc[i][j] = __builtin_amdgcn_mfma_f32_16x16x32_bf16(av[i], bv[j], acc[i][j], 0, 0, 0);
    __builtin_amdgcn_s_setprio(0);
    __builtin_amdgcn_sched_barrier(0);
    S_BARRIER();
#pragma unroll
    for (int i = 0; i < 4; ++i) av[i] = ldA(pc, wm + 64 + i * 16 + frow);
    if (T + 2 < nt) {
      stageB(pf, (T + 2) * 32);
      wait_pref();
    } else if (T + 1 < nt) {
      asm volatile("s_waitcnt vmcnt(0)" ::: "memory");
    }
    S_BARRIER();
    WAIT_LGKM0();
    __builtin_amdgcn_s_setprio(1);
#pragma unroll
    for (int i = 0; i < 4; ++i)
#pragma unroll
      for (int j = 0; j < 3; ++j)
        acc[4 + i][j] = __builtin_amdgcn_mfma_f32_16x16x32_bf16(av[i], bv[j], acc[4 + i][j], 0, 0, 0);
    __builtin_amdgcn_s_setprio(0);
    __builtin_amdgcn_sched_barrier(0);
    S_BARRIER();
    unsigned short* t = pc; pc = pn; pn = pf; pf = t;
  }

  const int cr = (lane >> 4) * 4, cc = lane & 15;
  const int o_col = (txi * 4 + wv) * 16 + cc;
  const int gcol = g * 512 + o_col;
  const float bgr = bg[g * 1536 + o_col];
  const float bgc = bg[g * 1536 + 512 + o_col];
  const float bgu = bg[g * 1536 + 1024 + o_col];
#pragma unroll
  for (int mf = 0; mf < 8; ++mf) {
    const int r0 = tm + wm + mf * 16 + cr;
#pragma unroll
    for (int i = 0; i < 4; ++i) {
      const long long off = (long long)(r0 + i) * 4096 + gcol;
      float dt = bf2f(deterB[off]);
      float reset = sigmoid_fast(acc[mf][0][i] + bgr);
      float cand  = tanh_fast(reset * (acc[mf][1][i] + bgc));
      float upd   = sigmoid_fast(acc[mf][2][i] + bgu - 1.f);
      out[off] = upd * cand + (1.f - upd) * dt;
    }
  }
}

// ---------------------------------------------------------------------------
// fp32 -> bf16 cast for two buffers in one launch (4 elems / thread)
// ---------------------------------------------------------------------------
__global__ void cvt2_bf16_k(const float* __restrict__ sa, unsigned short* __restrict__ da, int n4a,
                            const float* __restrict__ sb, unsigned short* __restrict__ db, int n4b) {
  int i = blockIdx.x * 256 + threadIdx.x;
  const float* s; unsigned short* d;
  if (i < n4a) { s = sa; d = da; }
  else { i -= n4a; if (i >= n4b) return; s = sb; d = db; }
  float4 v = ((const float4*)s)[i];
  u16x4 o;
  o.x = f2bf(v.x); o.y = f2bf(v.y); o.z = f2bf(v.z); o.w = f2bf(v.w);
  ((u16x4*)d)[i] = o;
}

// ---------------------------------------------------------------------------
// Vectorized batched transpose + cast: src fp32 [z][R][C] -> dst bf16
// [z][C][R]. 32R x 128C tiles, float4 loads, u16x4 stores. R%32==0, C%128==0.
// ---------------------------------------------------------------------------
__global__ __launch_bounds__(256) void transpose_cvt(
    const float* __restrict__ src, unsigned short* __restrict__ dst, int R, int C) {
  __shared__ float t[32][132];
  const long long bOff = (long long)blockIdx.z * R * C;
  src += bOff; dst += bOff;
  const int c0 = blockIdx.x * 128, r0 = blockIdx.y * 32;
  const int tid = threadIdx.x;
  const int tx = tid & 31, ty = tid >> 5;
#pragma unroll
  for (int j = 0; j < 4; ++j) {
    int row = ty + j * 8;
    float4 v = *(const float4*)&src[(long long)(r0 + row) * C + c0 + tx * 4];
    *(float4*)&t[row][tx * 4] = v;
  }
  __syncthreads();
#pragma unroll
  for (int j = 0; j < 4; ++j) {
    int idx = j * 256 + tid;
    int c = idx >> 3, rg = idx & 7;
    u16x4 o;
    o.x = f2bf(t[rg * 4 + 0][c]); o.y = f2bf(t[rg * 4 + 1][c]);
    o.z = f2bf(t[rg * 4 + 2][c]); o.w = f2bf(t[rg * 4 + 3][c]);
    *(u16x4*)&dst[(long long)(c0 + c) * R + r0 + rg * 4] = o;
  }
}

// ---------------------------------------------------------------------------
// Wg transpose with gate-interleaved row permutation (vectorized):
// src [8][512][1536] f32 -> dst [8][1536 nn][512] bf16,
// nn = (o>>4)*48 + gate*16 + (o&15).
// ---------------------------------------------------------------------------
__global__ __launch_bounds__(256) void transpose_wg(
    const float* __restrict__ src, unsigned short* __restrict__ dst) {
  __shared__ float t[32][132];
  const int gz = blockIdx.z;
  src += (long long)gz * 512 * 1536;
  dst += (long long)gz * 1536 * 512;
  const int c0 = blockIdx.x * 128, r0 = blockIdx.y * 32;
  const int tid = threadIdx.x;
  const int tx = tid & 31, ty = tid >> 5;
#pragma unroll
  for (int j = 0; j < 4; ++j) {
    int row = ty + j * 8;
    float4 v = *(const float4*)&src[(long long)(r0 + row) * 1536 + c0 + tx * 4];
    *(float4*)&t[row][tx * 4] = v;
  }
  __syncthreads();
#pragma unroll
  for (int j = 0; j < 4; ++j) {
    int idx = j * 256 + tid;
    int c = idx >> 3, rg = idx & 7;
    int cc = c0 + c;
    int gate = cc >> 9, o = cc & 511;
    int nn = (o >> 4) * 48 + gate * 16 + (o & 15);
    u16x4 oo;
    oo.x = f2bf(t[rg * 4 + 0][c]); oo.y = f2bf(t[rg * 4 + 1][c]);
    oo.z = f2bf(t[rg * 4 + 2][c]); oo.w = f2bf(t[rg * 4 + 3][c]);
    *(u16x4*)&dst[(long long)nn * 512 + r0 + rg * 4] = oo;
  }
}

// ---------------------------------------------------------------------------
// Merged branch epilogues. blockIdx.y: 0 -> branch0 (sum SIX split-K f32
// partials: 4 in yP0 region + 2 in yPx region), 1 -> branch1, 2/3 ->
// branch2/3 (tiny-K fp32 GEMM). All: +bias -> RMSNorm(512) -> SiLU -> x.
// ---------------------------------------------------------------------------
__global__ __launch_bounds__(256) void branch_epi_k(
    const float* __restrict__ yP0, const float* __restrict__ yPx,
    const float* __restrict__ yP1,
    const float* __restrict__ b0, const float* __restrict__ g0,
    const float* __restrict__ b1, const float* __restrict__ g1,
    const float* __restrict__ action, const float* __restrict__ demb,
    const float* __restrict__ W2, const float* __restrict__ b2, const float* __restrict__ g2,
    const float* __restrict__ W3, const float* __restrict__ b3, const float* __restrict__ g3,
    unsigned short* __restrict__ x)
{
  const int row = blockIdx.x, br = blockIdx.y;
  const int tid = threadIdx.x, lane = tid & 63, wave = tid >> 6;
  __shared__ float red[4];
  __shared__ float a[32];
  float v0, v1;
  const float* gg;
  if (br == 0) {
    const float* p = yP0 + (long long)row * 512;
    const float* q = yPx + (long long)row * 512;
    v0 = b0[tid]; v1 = b0[tid + 256];
#pragma unroll
    for (int c = 0; c < 4; ++c) {
      v0 += p[c * 2097152 + tid];
      v1 += p[c * 2097152 + tid + 256];
    }
#pragma unroll
    for (int c = 0; c < 2; ++c) {
      v0 += q[c * 2097152 + tid];
      v1 += q[c * 2097152 + tid + 256];
    }
    gg = g0;
  } else if (br == 1) {
    const float* p = yP1 + (long long)row * 512;
    v0 = b1[tid] + p[tid];
    v1 = b1[tid + 256] + p[tid + 256];
    gg = g1;
  } else {
    const int K = (br == 3) ? 16 : 32;
    const float* W  = (br == 3) ? W3 : W2;
    const float* bb = (br == 3) ? b3 : b2;
    gg = (br == 3) ? g3 : g2;
    if (tid < K) {
      float t = (br == 3) ? demb[(long long)row * 16 + tid]
                          : action[(long long)row * 32 + tid];
      if (br == 2) t = t / fmaxf(fabsf(t), 1.f);
      a[tid] = t;
    }
    __syncthreads();
    v0 = bb[tid]; v1 = bb[tid + 256];
    for (int k = 0; k < K; ++k) {
      float av = a[k];
      v0 += av * W[k * 512 + tid];
      v1 += av * W[k * 512 + tid + 256];
    }
  }
  float ss = v0 * v0 + v1 * v1;
  for (int o = 32; o > 0; o >>= 1) ss += __shfl_xor(ss, o);
  if (lane == 0) red[wave] = ss;
  __syncthreads();
  float ms = (red[0] + red[1] + red[2] + red[3]) * (1.f / 512.f);
  float sc = rsqrtf(ms + 1e-4f);
  unsigned short* xr = x + (long long)row * 2048 + br * 512;
  xr[tid]       = f2bf(siluf_(v0 * sc * gg[tid]));
  xr[tid + 256] = f2bf(siluf_(v1 * sc * gg[tid + 256]));
}

// ---------------------------------------------------------------------------
// Full-width (4096) epilogue: y(bf16) + bias -> RMSNorm -> SiLU -> h(bf16).
// ---------------------------------------------------------------------------
__global__ __launch_bounds__(256) void epi_full_k(
    const unsigned short* __restrict__ y, const float* __restrict__ bias,
    const float* __restrict__ gw, unsigned short* __restrict__ h)
{
  const int row = blockIdx.x;
  __shared__ float red[4];
  const int tid = threadIdx.x, lane = tid & 63, wave = tid >> 6;
  const u16x8* yv = (const u16x8*)(y + (long long)row * 4096);
  u16x8 ta = yv[tid], tb = yv[256 + tid];
  float ba[8], bb8[8];
  *(float4*)&ba[0]  = *(const float4*)&bias[tid * 8];
  *(float4*)&ba[4]  = *(const float4*)&bias[tid * 8 + 4];
  *(float4*)&bb8[0] = *(const float4*)&bias[(256 + tid) * 8];
  *(float4*)&bb8[4] = *(const float4*)&bias[(256 + tid) * 8 + 4];
  float fa[8], fb[8];
  float ss = 0.f;
#pragma unroll
  for (int e = 0; e < 8; ++e) {
    fa[e] = bf2f(ta[e]) + ba[e];  ss += fa[e] * fa[e];
    fb[e] = bf2f(tb[e]) + bb8[e]; ss += fb[e] * fb[e];
  }
  for (int o = 32; o > 0; o >>= 1) ss += __shfl_xor(ss, o);
  if (lane == 0) red[wave] = ss;
  __syncthreads();
  float ms = (red[0] + red[1] + red[2] + red[3]) * (1.f / 4096.f);
  float sc = rsqrtf(ms + 1e-4f);
  float ga[8], gb8[8];
  *(float4*)&ga[0]  = *(const float4*)&gw[tid * 8];
  *(float4*)&ga[4]  = *(const float4*)&gw[tid * 8 + 4];
  *(float4*)&gb8[0] = *(const float4*)&gw[(256 + tid) * 8];
  *(float4*)&gb8[4] = *(const float4*)&gw[(256 + tid) * 8 + 4];
  u16x8 oa, ob;
#pragma unroll
  for (int e = 0; e < 8; ++e) {
    oa[e] = f2bf(siluf_(fa[e] * sc * ga[e]));
    ob[e] = f2bf(siluf_(fb[e] * sc * gb8[e]));
  }
  u16x8* hv = (u16x8*)(h + (long long)row * 4096);
  hv[tid] = oa;
  hv[256 + tid] = ob;
}

// ---------------------------------------------------------------------------
extern "C" void kernel_launch(void* const* d_in, const int* in_sizes, int n_in,
                              void* d_out, int out_size, void* d_ws, size_t ws_size,
                              hipStream_t stream) {
  const float* stoch  = (const float*)d_in[0];
  const float* deter  = (const float*)d_in[1];
  const float* action = (const float*)d_in[2];
  const float* demb   = (const float*)d_in[3];
  const float* W0 = (const float*)d_in[4];
  const float* b0 = (const float*)d_in[5];
  const float* g0 = (const float*)d_in[6];
  const float* W1 = (const float*)d_in[7];
  const float* b1 = (const float*)d_in[8];
  const float* g1 = (const float*)d_in[9];
  const float* W2 = (const float*)d_in[10];
  const float* b2 = (const float*)d_in[11];
  const float* g2 = (const float*)d_in[12];
  const float* W3 = (const float*)d_in[13];
  const float* b3 = (const float*)d_in[14];
  const float* g3 = (const float*)d_in[15];
  const float* Wh0 = (const float*)d_in[16];
  const float* bh0 = (const float*)d_in[17];
  const float* gh0 = (const float*)d_in[18];
  const float* Wh1 = (const float*)d_in[19];
  const float* bh1 = (const float*)d_in[20];
  const float* gh1 = (const float*)d_in[21];
  const float* Wg  = (const float*)d_in[22];
  const float* bg  = (const float*)d_in[23];
  float* out = (float*)d_out;

  // Layout (bytes). deterB lives to the end (gemm_gru blend input).
  // Branch0 split-K partials: 4 slices in yP0 region + 2 in hB region (hB is
  // only written later by epi_full). Wgt overlays dead Wh0t after hidden0.
  char* ws = (char*)d_ws;
  unsigned short* deterB = (unsigned short*)(ws + 0);          // 33.55 MB, whole run
  unsigned short* stochB = (unsigned short*)(ws + 33554432);   //  8.39 MB
  unsigned short* W0t    = (unsigned short*)(ws + 41943040);   //  4.19 MB
  unsigned short* W1t    = (unsigned short*)(ws + 46137344);   //  1.05 MB
  unsigned short* xB     = (unsigned short*)(ws + 47185920);   // 16.78 MB
  float*          yP0    = (float*)(ws + 63963136);            // 33.55 MB: 4 partials (early)
  unsigned short* yB     = (unsigned short*)(ws + 63963136);   // 33.55 MB (late)
  float*          yP1    = (float*)(ws + 97517568);            //  8.39 MB
  unsigned short* Wh0t   = (unsigned short*)(ws + 105906176);  // 20.97 MB (dead after hidden0)
  unsigned short* Wgt    = (unsigned short*)(ws + 105906176);  // 12.58 MB (late)
  unsigned short* Wh1t   = (unsigned short*)(ws + 126877696);  //  4.19 MB
  unsigned short* hB     = (unsigned short*)(ws + 134217728);  // 33.55 MB
  float*          yPx    = (float*)(ws + 134217728);           // 16.78 MB: partials 4,5 (early)
  (void)in_sizes; (void)n_in; (void)out_size; (void)ws_size;

  dim3 b256(256);
  dim3 b512(512);
  cvt2_bf16_k<<<dim3(20480), b256, 0, stream>>>(deter, deterB, 4194304,
                                                stoch, stochB, 1048576);
  transpose_cvt<<<dim3(4, 128, 1), b256, 0, stream>>>(W0,  W0t,  4096, 512);
  transpose_cvt<<<dim3(4, 32, 1),  b256, 0, stream>>>(W1,  W1t,  1024, 512);
  // branches 0+1: split-K x6 for branch0 (K=4096 -> {704,704,704,672,672,640})
  // + branch1 (K=1024). Grid 224 wg.
  {
    const int k0s[6]   = {0, 704, 1408, 2112, 2784, 3456};
    const int klen[6]  = {704, 704, 704, 672, 672, 640};
    BPack p;
    for (int z = 0; z < 6; ++z) {
      float* part = (z < 4) ? (yP0 + (long long)z * 2097152)
                            : (yPx + (long long)(z - 4) * 2097152);
      p.c[z] = { deterB + k0s[z], 4096, klen[z], W0t + k0s[z], 4096, part };
    }
    p.c[6] = { stochB, 1024, 1024, W1t, 1024, yP1 };
    gemm8_branch<<<dim3(2, 16, 7), b512, 0, stream>>>(p);
  }
  // all four branch epilogues in one launch
  branch_epi_k<<<dim3(4096, 4), b256, 0, stream>>>(yP0, yPx, yP1, b0, g0, b1, g1,
                                                   action, demb, W2, b2, g2, W3, b3, g3, xB);
  // hidden block layer 0: [deter_blk | x] @ Wh0
  transpose_cvt<<<dim3(4, 80, 8),  b256, 0, stream>>>(Wh0, Wh0t, 2560, 512);
  transpose_cvt<<<dim3(4, 16, 8),  b256, 0, stream>>>(Wh1, Wh1t, 512,  512);
  gemm8<<<dim3(2, 16, 8), b512, 0, stream>>>(deterB, 4096, 512, 512, xB, 2048, 2048,
                                             Wh0t, 2560, 512LL * 2560, yB, 4096, 512);
  // Wg transpose (gate-interleaved) after hidden0; overlays dead Wh0t
  transpose_wg<<<dim3(12, 16, 8), b256, 0, stream>>>(Wg, Wgt);
  epi_full_k<<<dim3(4096), b256, 0, stream>>>(yB, bh0, gh0, hB);
  // hidden block layer 1
  gemm8<<<dim3(2, 16, 8), b512, 0, stream>>>(hB, 4096, 512, 512, nullptr, 0, 0,
                                             Wh1t, 512, 512LL * 512, yB, 4096, 512);
  epi_full_k<<<dim3(4096), b256, 0, stream>>>(yB, bh1, gh1, hB);
  // fused gates GEMM + GRU combine -> out (fp32); one group per XCD
  gemm_gru<<<dim3(8, 16, 8), b512, 0, stream>>>(hB, Wgt, bg, deterB, out);
}